// Round 1
// baseline (4312.035 us; speedup 1.0000x reference)
//
#include <hip/hip_runtime.h>
#include <math.h>

#define BATCH 256
#define SEQ   196
#define EMB   256
#define HEADS 8
#define HDIM  32
#define NBLK  4
#define FDIM  1024
#define NQB   8
#define NCLS  10
#define MROWS (BATCH*SEQ)   // 50176 = 64*784

// ------------------------------------------------------------------
// Positional encoding table (computed fresh every launch; tiny)
// ------------------------------------------------------------------
__global__ void pe_kernel(float* __restrict__ pe) {
    int s = blockIdx.x, e = threadIdx.x;
    int j2 = (e >> 1) * 2;
    float dv  = expf(-(float)j2 * (logf(10000.0f) / (float)EMB));
    float ang = (float)s * dv;
    pe[s * EMB + e] = (e & 1) ? cosf(ang) : sinf(ang);
}

// ------------------------------------------------------------------
// Fused: depthwise 2x2 s2 conv + pointwise 1x1 conv + channel-major
// reshape + embed (K=4) + bias + positional encoding  ->  h
// One block per (b,s) token, one thread per embedding dim.
// ------------------------------------------------------------------
__global__ __launch_bounds__(256) void embed_kernel(
    const float* __restrict__ x,   const float* __restrict__ qw,
    const float* __restrict__ qb,  const float* __restrict__ pw,
    const float* __restrict__ pb,  const float* __restrict__ ew,
    const float* __restrict__ eb,  const float* __restrict__ pe,
    float* __restrict__ h)
{
    int bs = blockIdx.x;
    int b  = bs / SEQ;
    int s  = bs % SEQ;
    int e  = threadIdx.x;

    // torch .view semantics: flat = 4*s + c over (co,hh,ww) of a (4,14,14) map
    int co    = s / 49;
    int pbase = (s % 49) * 4;

    float feat[4];
#pragma unroll
    for (int c = 0; c < 4; ++c) {
        int p  = pbase + c;
        int hh = p / 14, ww = p % 14;
        float dw[4];
#pragma unroll
        for (int ci = 0; ci < 4; ++ci) {
            const float* xp = x + (((size_t)b * 4 + ci) * 28 + hh * 2) * 28 + ww * 2;
            dw[ci] = qb[ci] + xp[0]  * qw[ci * 4 + 0] + xp[1]  * qw[ci * 4 + 1]
                            + xp[28] * qw[ci * 4 + 2] + xp[29] * qw[ci * 4 + 3];
        }
        feat[c] = pb[co] + pw[co * 4 + 0] * dw[0] + pw[co * 4 + 1] * dw[1]
                         + pw[co * 4 + 2] * dw[2] + pw[co * 4 + 3] * dw[3];
    }

    float4 w4 = *(const float4*)(ew + e * 4);
    float v = eb[e] + feat[0] * w4.x + feat[1] * w4.y + feat[2] * w4.z + feat[3] * w4.w;
    h[(size_t)bs * EMB + e] = v + pe[s * EMB + e];
}

// ------------------------------------------------------------------
// Generic tiled fp32 GEMM:  C[M,N] = A[M,K] @ W[N,K]^T + bias (+R)
// BM=BN=64, BK=16, 256 threads, 4x4 micro-tile per thread.
// M,N multiples of 64; K multiple of 16 (holds for all call sites).
// ------------------------------------------------------------------
#define BM 64
#define BN 64
#define BK 16

__global__ __launch_bounds__(256) void gemm_kernel(
    const float* __restrict__ A, const float* __restrict__ W,
    const float* __restrict__ bias, const float* __restrict__ R,
    float* __restrict__ C, int M, int N, int K)
{
    __shared__ float As[BK][BM + 4];   // +4 pad keeps rows 16B-aligned
    __shared__ float Bs[BK][BN + 4];

    int t  = threadIdx.x;
    int tx = t & 15, ty = t >> 4;
    int row0 = blockIdx.y * BM;
    int col0 = blockIdx.x * BN;

    int lr = t >> 2;          // 0..63 : tile row
    int lk = (t & 3) * 4;     // 0,4,8,12 : k sub-group

    const float* Aptr = A + (size_t)(row0 + lr) * K + lk;
    const float* Wptr = W + (size_t)(col0 + lr) * K + lk;

    float acc[4][4] = {};

    for (int k0 = 0; k0 < K; k0 += BK) {
        float4 av = *(const float4*)(Aptr + k0);
        float4 wv = *(const float4*)(Wptr + k0);
        __syncthreads();                      // protect prior iter reads
        As[lk + 0][lr] = av.x; As[lk + 1][lr] = av.y;
        As[lk + 2][lr] = av.z; As[lk + 3][lr] = av.w;
        Bs[lk + 0][lr] = wv.x; Bs[lk + 1][lr] = wv.y;
        Bs[lk + 2][lr] = wv.z; Bs[lk + 3][lr] = wv.w;
        __syncthreads();
#pragma unroll
        for (int kk = 0; kk < BK; ++kk) {
            float4 a4 = *(const float4*)&As[kk][ty * 4];
            float4 b4 = *(const float4*)&Bs[kk][tx * 4];
            float a_[4] = {a4.x, a4.y, a4.z, a4.w};
            float b_[4] = {b4.x, b4.y, b4.z, b4.w};
#pragma unroll
            for (int i = 0; i < 4; ++i)
#pragma unroll
                for (int j = 0; j < 4; ++j)
                    acc[i][j] += a_[i] * b_[j];
        }
    }

    float4 bb = *(const float4*)(bias + col0 + tx * 4);
#pragma unroll
    for (int i = 0; i < 4; ++i) {
        size_t roff = (size_t)(row0 + ty * 4 + i) * N + col0 + tx * 4;
        float4 r = {0.f, 0.f, 0.f, 0.f};
        if (R) r = *(const float4*)(R + roff);
        float4 o;
        o.x = acc[i][0] + bb.x + r.x;
        o.y = acc[i][1] + bb.y + r.y;
        o.z = acc[i][2] + bb.z + r.z;
        o.w = acc[i][3] + bb.w + r.w;
        *(float4*)(C + roff) = o;
    }
}

// ------------------------------------------------------------------
// Fused attention per (b,h): K/V staged in LDS, one thread per query
// row, online softmax. Writes o in (b,s,e) layout for the out-proj.
// ------------------------------------------------------------------
__global__ __launch_bounds__(256) void attn_kernel(
    const float* __restrict__ qkv, float* __restrict__ o)
{
    __shared__ float Ks[SEQ * HDIM];
    __shared__ float Vs[SEQ * HDIM];

    int bh = blockIdx.x;
    int b  = bh >> 3;
    int hh = bh & 7;
    const float* base = qkv + (size_t)b * SEQ * 768 + hh * HDIM;

    for (int idx = threadIdx.x; idx < SEQ * HDIM; idx += 256) {
        int j = idx >> 5, d = idx & 31;
        Ks[idx] = base[(size_t)j * 768 + 256 + d];
        Vs[idx] = base[(size_t)j * 768 + 512 + d];
    }
    __syncthreads();

    int s = threadIdx.x;
    if (s < SEQ) {
        float q[HDIM];
        const float* qp = base + (size_t)s * 768;
#pragma unroll
        for (int d = 0; d < HDIM; ++d) q[d] = qp[d] * 0.17677669529663687f;

        float m = -1e30f, l = 0.f;
        float acc[HDIM] = {};
        for (int j = 0; j < SEQ; ++j) {
            const float* kr = &Ks[j * HDIM];
            float sc = 0.f;
#pragma unroll
            for (int d = 0; d < HDIM; ++d) sc += q[d] * kr[d];
            float mn   = fmaxf(m, sc);
            float corr = __expf(m - mn);
            float p    = __expf(sc - mn);
            l = l * corr + p;
            const float* vr = &Vs[j * HDIM];
#pragma unroll
            for (int d = 0; d < HDIM; ++d) acc[d] = acc[d] * corr + p * vr[d];
            m = mn;
        }
        float invl = 1.f / l;
        float* op = o + ((size_t)b * SEQ + s) * EMB + hh * HDIM;
#pragma unroll
        for (int d = 0; d < HDIM; ++d) op[d] = acc[d] * invl;
    }
}

// ------------------------------------------------------------------
// LayerNorm over E=256, one wave (64 lanes x float4) per row, in place.
// Optionally emits qm = cos(y[0:8]) * cos(theta[0:8]) for the q-FFN.
// ------------------------------------------------------------------
__global__ __launch_bounds__(256) void ln_kernel(
    float* __restrict__ h, const float* __restrict__ g,
    const float* __restrict__ bta, const float* __restrict__ theta,
    float* __restrict__ qm)
{
    int wid  = threadIdx.x >> 6;
    int lane = threadIdx.x & 63;
    int row  = blockIdx.x * 4 + wid;

    float* hp = h + (size_t)row * EMB + lane * 4;
    float4 xv = *(const float4*)hp;

    float s1 = xv.x + xv.y + xv.z + xv.w;
    float s2 = xv.x * xv.x + xv.y * xv.y + xv.z * xv.z + xv.w * xv.w;
#pragma unroll
    for (int off = 32; off; off >>= 1) {
        s1 += __shfl_xor(s1, off);
        s2 += __shfl_xor(s2, off);
    }
    float mean = s1 * (1.0f / 256.0f);
    float var  = s2 * (1.0f / 256.0f) - mean * mean;
    float inv  = rsqrtf(var + 1e-5f);

    float4 gv = *(const float4*)(g   + lane * 4);
    float4 bv = *(const float4*)(bta + lane * 4);
    float4 y;
    y.x = (xv.x - mean) * inv * gv.x + bv.x;
    y.y = (xv.y - mean) * inv * gv.y + bv.y;
    y.z = (xv.z - mean) * inv * gv.z + bv.z;
    y.w = (xv.w - mean) * inv * gv.w + bv.w;
    *(float4*)hp = y;

    if (qm && lane < 2) {
        float yv[4] = {y.x, y.y, y.z, y.w};
        float* qp = qm + (size_t)row * NQB + lane * 4;
#pragma unroll
        for (int j = 0; j < 4; ++j)
            qp[j] = __cosf(yv[j]) * __cosf(theta[lane * 4 + j]);
    }
}

// ------------------------------------------------------------------
// Fused quantum FFN: h += relu(qm @ l1^T + b1) @ l2^T + b2
// Standard 64x64x16 GEMM over K=1024, but the A tile (activations)
// is computed on the fly from 8 qm values/row -> no 205MB act buffer.
// ------------------------------------------------------------------
__global__ __launch_bounds__(256) void ffn_kernel(
    const float* __restrict__ qm,  const float* __restrict__ l1w,
    const float* __restrict__ l1b, const float* __restrict__ l2w,
    const float* __restrict__ l2b, float* __restrict__ h)
{
    __shared__ float As[BK][BM + 4];
    __shared__ float Bs[BK][BN + 4];
    __shared__ float qmT[NQB][BM + 4];   // transposed to avoid bank conflicts

    int t  = threadIdx.x;
    int tx = t & 15, ty = t >> 4;
    int row0 = blockIdx.y * BM;
    int col0 = blockIdx.x * BN;

    // stage qm rows for this M-tile (transposed)
    {
        float2 v = *(const float2*)(qm + (size_t)row0 * NQB + t * 2);
        int m = t >> 2;               // t*2/8
        int q = (t & 3) * 2;
        qmT[q][m]     = v.x;
        qmT[q + 1][m] = v.y;
    }

    int lr = t >> 2;
    int lk = (t & 3) * 4;
    const float* Wptr = l2w + (size_t)(col0 + lr) * FDIM + lk;

    int akk = t >> 4;          // 0..15 : which k row of the act tile
    int amb = (t & 15) * 4;    // 0..60 : which 4 m's

    float acc[4][4] = {};

    for (int k0 = 0; k0 < FDIM; k0 += BK) {
        float4 wv = *(const float4*)(Wptr + k0);
        const float4* l1p = (const float4*)(l1w + (size_t)(k0 + akk) * NQB);
        float4 w0 = l1p[0], w1 = l1p[1];
        float b1  = l1b[k0 + akk];
        __syncthreads();
        // on-the-fly activation tile: act[kk][m] = relu(b1 + qm[m].l1w[kk])
#pragma unroll
        for (int u = 0; u < 4; ++u) {
            int mm = amb + u;
            float a = b1
                + qmT[0][mm] * w0.x + qmT[1][mm] * w0.y
                + qmT[2][mm] * w0.z + qmT[3][mm] * w0.w
                + qmT[4][mm] * w1.x + qmT[5][mm] * w1.y
                + qmT[6][mm] * w1.z + qmT[7][mm] * w1.w;
            As[akk][mm] = fmaxf(a, 0.f);
        }
        Bs[lk + 0][lr] = wv.x; Bs[lk + 1][lr] = wv.y;
        Bs[lk + 2][lr] = wv.z; Bs[lk + 3][lr] = wv.w;
        __syncthreads();
#pragma unroll
        for (int kk = 0; kk < BK; ++kk) {
            float4 a4 = *(const float4*)&As[kk][ty * 4];
            float4 b4 = *(const float4*)&Bs[kk][tx * 4];
            float a_[4] = {a4.x, a4.y, a4.z, a4.w};
            float b_[4] = {b4.x, b4.y, b4.z, b4.w};
#pragma unroll
            for (int i = 0; i < 4; ++i)
#pragma unroll
                for (int j = 0; j < 4; ++j)
                    acc[i][j] += a_[i] * b_[j];
        }
    }

    float4 bb = *(const float4*)(l2b + col0 + tx * 4);
#pragma unroll
    for (int i = 0; i < 4; ++i) {
        size_t roff = (size_t)(row0 + ty * 4 + i) * EMB + col0 + tx * 4;
        float4 r = *(const float4*)(h + roff);
        float4 o;
        o.x = r.x + acc[i][0] + bb.x;
        o.y = r.y + acc[i][1] + bb.y;
        o.z = r.z + acc[i][2] + bb.z;
        o.w = r.w + acc[i][3] + bb.w;
        *(float4*)(h + roff) = o;
    }
}

// ------------------------------------------------------------------
// Mean-pool over S then 10-way classifier. One block per batch item.
// ------------------------------------------------------------------
__global__ __launch_bounds__(256) void pool_cls_kernel(
    const float* __restrict__ h, const float* __restrict__ cw,
    const float* __restrict__ cb, float* __restrict__ out)
{
    __shared__ float pooled[EMB];
    int b = blockIdx.x;
    int e = threadIdx.x;
    float s = 0.f;
    const float* hp = h + (size_t)b * SEQ * EMB + e;
    for (int j = 0; j < SEQ; ++j) s += hp[(size_t)j * EMB];
    pooled[e] = s * (1.0f / (float)SEQ);
    __syncthreads();
    if (e < NCLS) {
        float acc = cb[e];
        const float* wr = cw + e * EMB;
        for (int k = 0; k < EMB; ++k) acc += pooled[k] * wr[k];
        out[b * NCLS + e] = acc;
    }
}

// ------------------------------------------------------------------
extern "C" void kernel_launch(void* const* d_in, const int* in_sizes, int n_in,
                              void* d_out, int out_size, void* d_ws, size_t ws_size,
                              hipStream_t stream)
{
    const float* x         = (const float*)d_in[0];
    const float* qfilter_w = (const float*)d_in[1];
    const float* qfilter_b = (const float*)d_in[2];
    const float* pw_w      = (const float*)d_in[3];
    const float* pw_b      = (const float*)d_in[4];
    const float* embed_w   = (const float*)d_in[5];
    const float* embed_b   = (const float*)d_in[6];
    const float* in_proj_w = (const float*)d_in[7];
    const float* in_proj_b = (const float*)d_in[8];
    const float* out_w     = (const float*)d_in[9];
    const float* out_b     = (const float*)d_in[10];
    const float* theta     = (const float*)d_in[11];
    const float* l1_w      = (const float*)d_in[12];
    const float* l1_b      = (const float*)d_in[13];
    const float* l2_w      = (const float*)d_in[14];
    const float* l2_b      = (const float*)d_in[15];
    const float* ln1_g     = (const float*)d_in[16];
    const float* ln1_b     = (const float*)d_in[17];
    const float* ln2_g     = (const float*)d_in[18];
    const float* ln2_b     = (const float*)d_in[19];
    const float* cls_w     = (const float*)d_in[20];
    const float* cls_b     = (const float*)d_in[21];

    float* ws  = (float*)d_ws;
    float* h   = ws;                                  // 50176*256
    float* qkv = h   + (size_t)MROWS * EMB;           // 50176*768
    float* o   = qkv + (size_t)MROWS * 768;           // 50176*256
    float* qm  = o   + (size_t)MROWS * EMB;           // 50176*8
    float* pe  = qm  + (size_t)MROWS * NQB;           // 196*256

    pe_kernel<<<SEQ, EMB, 0, stream>>>(pe);
    embed_kernel<<<MROWS, 256, 0, stream>>>(x, qfilter_w, qfilter_b,
                                            pw_w, pw_b, embed_w, embed_b, pe, h);

    for (int i = 0; i < NBLK; ++i) {
        // QKV projection: [50176,256] @ [768,256]^T
        gemm_kernel<<<dim3(768 / BN, MROWS / BM), 256, 0, stream>>>(
            h, in_proj_w + (size_t)i * 768 * EMB, in_proj_b + i * 768,
            nullptr, qkv, MROWS, 768, EMB);
        // attention
        attn_kernel<<<BATCH * HEADS, 256, 0, stream>>>(qkv, o);
        // out projection + residual:  h = h + o @ W^T + b
        gemm_kernel<<<dim3(EMB / BN, MROWS / BM), 256, 0, stream>>>(
            o, out_w + (size_t)i * EMB * EMB, out_b + i * EMB,
            h, h, MROWS, EMB, EMB);
        // LN1 (+ qm extraction)
        ln_kernel<<<MROWS / 4, 256, 0, stream>>>(
            h, ln1_g + i * EMB, ln1_b + i * EMB, theta + i * NQB, qm);
        // fused quantum FFN + residual
        ffn_kernel<<<dim3(EMB / BN, MROWS / BM), 256, 0, stream>>>(
            qm, l1_w + (size_t)i * FDIM * NQB, l1_b + i * FDIM,
            l2_w + (size_t)i * EMB * FDIM, l2_b + i * EMB, h);
        // LN2
        ln_kernel<<<MROWS / 4, 256, 0, stream>>>(
            h, ln2_g + i * EMB, ln2_b + i * EMB, nullptr, nullptr);
    }

    pool_cls_kernel<<<BATCH, EMB, 0, stream>>>(h, cls_w, cls_b, (float*)d_out);
}

// Round 2
// 2906.198 us; speedup vs baseline: 1.4837x; 1.4837x over previous
//
#include <hip/hip_runtime.h>
#include <math.h>

#define BATCH 256
#define SEQ   196
#define EMB   256
#define HEADS 8
#define HDIM  32
#define NBLK  4
#define FDIM  1024
#define NQB   8
#define NCLS  10
#define MROWS (BATCH*SEQ)   // 50176 = 392*128

typedef __attribute__((ext_vector_type(8))) short  short8;   // 8 bf16 (4 VGPRs)
typedef __attribute__((ext_vector_type(4))) float  floatx4;  // MFMA acc

// fp32 -> bf16 RNE
__device__ __forceinline__ unsigned short f2b(float f) {
    unsigned u = __builtin_bit_cast(unsigned, f);
    u += 0x7fffu + ((u >> 16) & 1u);
    return (unsigned short)(u >> 16);
}

// async global->LDS, 16B per lane. LDS dest must be wave-uniform base; HW adds lane*16.
__device__ __forceinline__ void gl_lds16(const void* g, void* l) {
    __builtin_amdgcn_global_load_lds(
        (const __attribute__((address_space(1))) unsigned int*)g,
        (__attribute__((address_space(3))) unsigned int*)l, 16, 0, 0);
}

// ------------------------------------------------------------------
// Positional encoding table
// ------------------------------------------------------------------
__global__ void pe_kernel(float* __restrict__ pe) {
    int s = blockIdx.x, e = threadIdx.x;
    int j2 = (e >> 1) * 2;
    float dv  = expf(-(float)j2 * (logf(10000.0f) / (float)EMB));
    float ang = (float)s * dv;
    pe[s * EMB + e] = (e & 1) ? cosf(ang) : sinf(ang);
}

// ------------------------------------------------------------------
// fp32 -> bf16 bulk convert (weights), n % 4 == 0
// ------------------------------------------------------------------
__global__ __launch_bounds__(256) void cvt_kernel(
    const float* __restrict__ src, unsigned short* __restrict__ dst, int n)
{
    int i = (blockIdx.x * 256 + threadIdx.x) * 4;
    if (i < n) {
        float4 v = *(const float4*)(src + i);
        ushort4 o;
        o.x = f2b(v.x); o.y = f2b(v.y); o.z = f2b(v.z); o.w = f2b(v.w);
        *(ushort4*)(dst + i) = o;
    }
}

// ------------------------------------------------------------------
// Fused conv+conv+reshape+embed+PE -> h (fp32) and hb (bf16)
// ------------------------------------------------------------------
__global__ __launch_bounds__(256) void embed_kernel(
    const float* __restrict__ x,   const float* __restrict__ qw,
    const float* __restrict__ qb,  const float* __restrict__ pw,
    const float* __restrict__ pb,  const float* __restrict__ ew,
    const float* __restrict__ eb,  const float* __restrict__ pe,
    float* __restrict__ h, unsigned short* __restrict__ hb)
{
    int bs = blockIdx.x;
    int b  = bs / SEQ;
    int s  = bs % SEQ;
    int e  = threadIdx.x;

    int co    = s / 49;
    int pbase = (s % 49) * 4;

    float feat[4];
#pragma unroll
    for (int c = 0; c < 4; ++c) {
        int p  = pbase + c;
        int hh = p / 14, ww = p % 14;
        float dw[4];
#pragma unroll
        for (int ci = 0; ci < 4; ++ci) {
            const float* xp = x + (((size_t)b * 4 + ci) * 28 + hh * 2) * 28 + ww * 2;
            dw[ci] = qb[ci] + xp[0]  * qw[ci * 4 + 0] + xp[1]  * qw[ci * 4 + 1]
                            + xp[28] * qw[ci * 4 + 2] + xp[29] * qw[ci * 4 + 3];
        }
        feat[c] = pb[co] + pw[co * 4 + 0] * dw[0] + pw[co * 4 + 1] * dw[1]
                         + pw[co * 4 + 2] * dw[2] + pw[co * 4 + 3] * dw[3];
    }

    float4 w4 = *(const float4*)(ew + e * 4);
    float v = eb[e] + feat[0] * w4.x + feat[1] * w4.y + feat[2] * w4.z + feat[3] * w4.w
            + pe[s * EMB + e];
    h[(size_t)bs * EMB + e]  = v;
    hb[(size_t)bs * EMB + e] = f2b(v);
}

// ------------------------------------------------------------------
// bf16 MFMA GEMM: C[M,N] = A[M,K]bf16 @ W[N,K]bf16^T + bias (+R), fp32 out.
// 128x128 tile, BK=32, 256 thr = 4 waves, each wave 64x64 via 4x4 16x16x32.
// M%128==0, N%128==0, K%32==0.
// ------------------------------------------------------------------
__global__ __launch_bounds__(256) void bgemm_kernel(
    const unsigned short* __restrict__ A, const unsigned short* __restrict__ W,
    const float* __restrict__ bias, const float* __restrict__ R,
    float* __restrict__ C, int M, int N, int K)
{
    __shared__ unsigned short As[128 * 32];
    __shared__ unsigned short Bs[128 * 32];

    int t = threadIdx.x;
    int w = t >> 6, l = t & 63;
    int quad = l >> 4, lane16 = l & 15;
    int m0 = blockIdx.y * 128, n0 = blockIdx.x * 128;
    int mq = (w & 1) * 64, nq = (w >> 1) * 64;

    // staging: wave w covers rows [w*32, w*32+32); lane l -> row w*32+q*16+l/4, col (l&3)*8
    int srow = w * 32 + (l >> 2);
    int scol = (l & 3) * 8;
    const unsigned short* Abase = A + (size_t)(m0 + srow) * K + scol;
    const unsigned short* Wbase = W + (size_t)(n0 + srow) * K + scol;
    unsigned short* AsW = As + w * 1024;   // (w*32)*32
    unsigned short* BsW = Bs + w * 1024;

    floatx4 acc[4][4];
#pragma unroll
    for (int i = 0; i < 4; ++i)
#pragma unroll
        for (int j = 0; j < 4; ++j) acc[i][j] = (floatx4){0.f, 0.f, 0.f, 0.f};

    for (int k0 = 0; k0 < K; k0 += 32) {
        __syncthreads();
        gl_lds16(Abase + k0,              AsW);
        gl_lds16(Abase + (size_t)16 * K + k0, AsW + 512);
        gl_lds16(Wbase + k0,              BsW);
        gl_lds16(Wbase + (size_t)16 * K + k0, BsW + 512);
        __syncthreads();

        short8 af[4], bf[4];
#pragma unroll
        for (int i = 0; i < 4; ++i)
            af[i] = *(const short8*)&As[(mq + i * 16 + lane16) * 32 + quad * 8];
#pragma unroll
        for (int j = 0; j < 4; ++j)
            bf[j] = *(const short8*)&Bs[(nq + j * 16 + lane16) * 32 + quad * 8];
#pragma unroll
        for (int i = 0; i < 4; ++i)
#pragma unroll
            for (int j = 0; j < 4; ++j)
                acc[i][j] = __builtin_amdgcn_mfma_f32_16x16x32_bf16(
                                af[i], bf[j], acc[i][j], 0, 0, 0);
    }

#pragma unroll
    for (int j = 0; j < 4; ++j) {
        int col = n0 + nq + j * 16 + lane16;
        float bb = bias[col];
#pragma unroll
        for (int i = 0; i < 4; ++i) {
#pragma unroll
            for (int r = 0; r < 4; ++r) {
                int row = m0 + mq + i * 16 + quad * 4 + r;
                size_t off = (size_t)row * N + col;
                float v = acc[i][j][r] + bb;
                if (R) v += R[off];
                C[off] = v;
            }
        }
    }
}

// ------------------------------------------------------------------
// Fused quantum FFN (bf16 MFMA):
//   h += relu(qm @ l1^T + b1) @ l2^T + b2
// A-tile (activations) generated on the fly in bf16; W = l2 bf16 [256][1024].
// ------------------------------------------------------------------
__global__ __launch_bounds__(256) void ffnb_kernel(
    const float* __restrict__ qm,  const float* __restrict__ l1w,
    const float* __restrict__ l1b, const unsigned short* __restrict__ W,
    const float* __restrict__ l2b, float* __restrict__ h)
{
    __shared__ unsigned short As[128 * 32];
    __shared__ unsigned short Bs[128 * 32];

    int t = threadIdx.x;
    int w = t >> 6, l = t & 63;
    int quad = l >> 4, lane16 = l & 15;
    int m0 = blockIdx.y * 128, n0 = blockIdx.x * 128;
    int mq = (w & 1) * 64, nq = (w >> 1) * 64;

    int srow = w * 32 + (l >> 2);
    int scol = (l & 3) * 8;
    const unsigned short* Wbase = W + (size_t)(n0 + srow) * FDIM + scol;
    unsigned short* BsW = Bs + w * 1024;

    // act generation: thread handles row am, kk range [ak, ak+16)
    int am = t >> 1;
    int ak = (t & 1) * 16;
    floatx4 q0 = *(const floatx4*)(qm + (size_t)(m0 + am) * NQB);
    floatx4 q1 = *(const floatx4*)(qm + (size_t)(m0 + am) * NQB + 4);
    unsigned short* arow = As + am * 32 + ak;

    floatx4 acc[4][4];
#pragma unroll
    for (int i = 0; i < 4; ++i)
#pragma unroll
        for (int j = 0; j < 4; ++j) acc[i][j] = (floatx4){0.f, 0.f, 0.f, 0.f};

    for (int k0 = 0; k0 < FDIM; k0 += 32) {
        __syncthreads();
        gl_lds16(Wbase + k0,                   BsW);
        gl_lds16(Wbase + (size_t)16 * FDIM + k0, BsW + 512);
#pragma unroll
        for (int kk = 0; kk < 16; ++kk) {
            int kabs = k0 + ak + kk;
            const floatx4* lp = (const floatx4*)(l1w + (size_t)kabs * NQB);
            floatx4 w0 = lp[0], w1 = lp[1];
            float a = l1b[kabs]
                + q0.x * w0.x + q0.y * w0.y + q0.z * w0.z + q0.w * w0.w
                + q1.x * w1.x + q1.y * w1.y + q1.z * w1.z + q1.w * w1.w;
            arow[kk] = f2b(fmaxf(a, 0.f));
        }
        __syncthreads();

        short8 af[4], bf[4];
#pragma unroll
        for (int i = 0; i < 4; ++i)
            af[i] = *(const short8*)&As[(mq + i * 16 + lane16) * 32 + quad * 8];
#pragma unroll
        for (int j = 0; j < 4; ++j)
            bf[j] = *(const short8*)&Bs[(nq + j * 16 + lane16) * 32 + quad * 8];
#pragma unroll
        for (int i = 0; i < 4; ++i)
#pragma unroll
            for (int j = 0; j < 4; ++j)
                acc[i][j] = __builtin_amdgcn_mfma_f32_16x16x32_bf16(
                                af[i], bf[j], acc[i][j], 0, 0, 0);
    }

#pragma unroll
    for (int j = 0; j < 4; ++j) {
        int col = n0 + nq + j * 16 + lane16;
        float bb = l2b[col];
#pragma unroll
        for (int i = 0; i < 4; ++i) {
#pragma unroll
            for (int r = 0; r < 4; ++r) {
                int row = m0 + mq + i * 16 + quad * 4 + r;
                size_t off = (size_t)row * EMB + col;
                h[off] = h[off] + acc[i][j][r] + bb;
            }
        }
    }
}

// ------------------------------------------------------------------
// Fused attention per (b,h): K/V in LDS, one thread per query row,
// online softmax. Writes o directly as bf16 in (b,s,e) layout.
// ------------------------------------------------------------------
__global__ __launch_bounds__(256) void attn_kernel(
    const float* __restrict__ qkv, unsigned short* __restrict__ ob)
{
    __shared__ float Ks[SEQ * HDIM];
    __shared__ float Vs[SEQ * HDIM];

    int bh = blockIdx.x;
    int b  = bh >> 3;
    int hh = bh & 7;
    const float* base = qkv + (size_t)b * SEQ * 768 + hh * HDIM;

    for (int idx = threadIdx.x; idx < SEQ * HDIM; idx += 256) {
        int j = idx >> 5, d = idx & 31;
        Ks[idx] = base[(size_t)j * 768 + 256 + d];
        Vs[idx] = base[(size_t)j * 768 + 512 + d];
    }
    __syncthreads();

    int s = threadIdx.x;
    if (s < SEQ) {
        float q[HDIM];
        const float* qp = base + (size_t)s * 768;
#pragma unroll
        for (int d = 0; d < HDIM; ++d) q[d] = qp[d] * 0.17677669529663687f;

        float m = -1e30f, ll = 0.f;
        float acc[HDIM] = {};
        for (int j = 0; j < SEQ; ++j) {
            const float* kr = &Ks[j * HDIM];
            float sc = 0.f;
#pragma unroll
            for (int d = 0; d < HDIM; ++d) sc += q[d] * kr[d];
            float mn   = fmaxf(m, sc);
            float corr = __expf(m - mn);
            float p    = __expf(sc - mn);
            ll = ll * corr + p;
            const float* vr = &Vs[j * HDIM];
#pragma unroll
            for (int d = 0; d < HDIM; ++d) acc[d] = acc[d] * corr + p * vr[d];
            m = mn;
        }
        float invl = 1.f / ll;
        unsigned short* op = ob + ((size_t)b * SEQ + s) * EMB + hh * HDIM;
#pragma unroll
        for (int d = 0; d < HDIM; ++d) op[d] = f2b(acc[d] * invl);
    }
}

// ------------------------------------------------------------------
// LayerNorm, one wave per row, in place. Optionally emits qm (ln1)
// or a bf16 copy of the output row (ln2).
// ------------------------------------------------------------------
__global__ __launch_bounds__(256) void ln_kernel(
    float* __restrict__ h, const float* __restrict__ g,
    const float* __restrict__ bta, const float* __restrict__ theta,
    float* __restrict__ qm, unsigned short* __restrict__ hb)
{
    int wid  = threadIdx.x >> 6;
    int lane = threadIdx.x & 63;
    int row  = blockIdx.x * 4 + wid;

    float* hp = h + (size_t)row * EMB + lane * 4;
    float4 xv = *(const float4*)hp;

    float s1 = xv.x + xv.y + xv.z + xv.w;
    float s2 = xv.x * xv.x + xv.y * xv.y + xv.z * xv.z + xv.w * xv.w;
#pragma unroll
    for (int off = 32; off; off >>= 1) {
        s1 += __shfl_xor(s1, off);
        s2 += __shfl_xor(s2, off);
    }
    float mean = s1 * (1.0f / 256.0f);
    float var  = s2 * (1.0f / 256.0f) - mean * mean;
    float inv  = rsqrtf(var + 1e-5f);

    float4 gv = *(const float4*)(g   + lane * 4);
    float4 bv = *(const float4*)(bta + lane * 4);
    float4 y;
    y.x = (xv.x - mean) * inv * gv.x + bv.x;
    y.y = (xv.y - mean) * inv * gv.y + bv.y;
    y.z = (xv.z - mean) * inv * gv.z + bv.z;
    y.w = (xv.w - mean) * inv * gv.w + bv.w;
    *(float4*)hp = y;

    if (qm && lane < 2) {
        float yv[4] = {y.x, y.y, y.z, y.w};
        float* qp = qm + (size_t)row * NQB + lane * 4;
#pragma unroll
        for (int j = 0; j < 4; ++j)
            qp[j] = __cosf(yv[j]) * __cosf(theta[lane * 4 + j]);
    }
    if (hb) {
        ushort4 o4;
        o4.x = f2b(y.x); o4.y = f2b(y.y); o4.z = f2b(y.z); o4.w = f2b(y.w);
        *(ushort4*)(hb + (size_t)row * EMB + lane * 4) = o4;
    }
}

// ------------------------------------------------------------------
// Mean-pool over S then classifier.
// ------------------------------------------------------------------
__global__ __launch_bounds__(256) void pool_cls_kernel(
    const float* __restrict__ h, const float* __restrict__ cw,
    const float* __restrict__ cb, float* __restrict__ out)
{
    __shared__ float pooled[EMB];
    int b = blockIdx.x;
    int e = threadIdx.x;
    float s = 0.f;
    const float* hp = h + (size_t)b * SEQ * EMB + e;
    for (int j = 0; j < SEQ; ++j) s += hp[(size_t)j * EMB];
    pooled[e] = s * (1.0f / (float)SEQ);
    __syncthreads();
    if (e < NCLS) {
        float acc = cb[e];
        const float* wr = cw + e * EMB;
        for (int k = 0; k < EMB; ++k) acc += pooled[k] * wr[k];
        out[b * NCLS + e] = acc;
    }
}

// ------------------------------------------------------------------
extern "C" void kernel_launch(void* const* d_in, const int* in_sizes, int n_in,
                              void* d_out, int out_size, void* d_ws, size_t ws_size,
                              hipStream_t stream)
{
    const float* x         = (const float*)d_in[0];
    const float* qfilter_w = (const float*)d_in[1];
    const float* qfilter_b = (const float*)d_in[2];
    const float* pw_w      = (const float*)d_in[3];
    const float* pw_b      = (const float*)d_in[4];
    const float* embed_w   = (const float*)d_in[5];
    const float* embed_b   = (const float*)d_in[6];
    const float* in_proj_w = (const float*)d_in[7];
    const float* in_proj_b = (const float*)d_in[8];
    const float* out_w     = (const float*)d_in[9];
    const float* out_b     = (const float*)d_in[10];
    const float* theta     = (const float*)d_in[11];
    const float* l1_w      = (const float*)d_in[12];
    const float* l1_b      = (const float*)d_in[13];
    const float* l2_w      = (const float*)d_in[14];
    const float* l2_b      = (const float*)d_in[15];
    const float* ln1_g     = (const float*)d_in[16];
    const float* ln1_b     = (const float*)d_in[17];
    const float* ln2_g     = (const float*)d_in[18];
    const float* ln2_b     = (const float*)d_in[19];
    const float* cls_w     = (const float*)d_in[20];
    const float* cls_b     = (const float*)d_in[21];

    char* ws = (char*)d_ws;
    float* h    = (float*)ws;                 ws += (size_t)MROWS * EMB * 4;   // 51.4MB
    float* qkv  = (float*)ws;                 ws += (size_t)MROWS * 768 * 4;   // 154.1MB
    float* qm   = (float*)ws;                 ws += (size_t)MROWS * NQB * 4;   // 1.6MB
    float* pe   = (float*)ws;                 ws += (size_t)SEQ * EMB * 4;
    unsigned short* hb  = (unsigned short*)ws; ws += (size_t)MROWS * EMB * 2;  // 25.7MB
    unsigned short* ob  = (unsigned short*)ws; ws += (size_t)MROWS * EMB * 2;  // 25.7MB
    unsigned short* wb_in = (unsigned short*)ws; ws += (size_t)NBLK * 768 * EMB * 2;
    unsigned short* wb_o  = (unsigned short*)ws; ws += (size_t)NBLK * EMB * EMB * 2;
    unsigned short* wb_l2 = (unsigned short*)ws; ws += (size_t)NBLK * EMB * FDIM * 2;

    // one-time per launch: PE table + weight conversion
    pe_kernel<<<SEQ, EMB, 0, stream>>>(pe);
    {
        int n1 = NBLK * 768 * EMB;   // 786432
        int n2 = NBLK * EMB * EMB;   // 262144
        int n3 = NBLK * EMB * FDIM;  // 1048576
        cvt_kernel<<<n1 / 1024, 256, 0, stream>>>(in_proj_w, wb_in, n1);
        cvt_kernel<<<n2 / 1024, 256, 0, stream>>>(out_w,     wb_o,  n2);
        cvt_kernel<<<n3 / 1024, 256, 0, stream>>>(l2_w,      wb_l2, n3);
    }

    embed_kernel<<<MROWS, 256, 0, stream>>>(x, qfilter_w, qfilter_b,
                                            pw_w, pw_b, embed_w, embed_b, pe, h, hb);

    for (int i = 0; i < NBLK; ++i) {
        // QKV projection: [50176,256]bf16 @ [768,256]bf16^T -> fp32
        bgemm_kernel<<<dim3(768 / 128, MROWS / 128), 256, 0, stream>>>(
            hb, wb_in + (size_t)i * 768 * EMB, in_proj_b + i * 768,
            nullptr, qkv, MROWS, 768, EMB);
        // attention (fp32 in, bf16 out)
        attn_kernel<<<BATCH * HEADS, 256, 0, stream>>>(qkv, ob);
        // out projection + residual: h = h + o @ W^T + b
        bgemm_kernel<<<dim3(EMB / 128, MROWS / 128), 256, 0, stream>>>(
            ob, wb_o + (size_t)i * EMB * EMB, out_b + i * EMB,
            h, h, MROWS, EMB, EMB);
        // LN1 (+ qm)
        ln_kernel<<<MROWS / 4, 256, 0, stream>>>(
            h, ln1_g + i * EMB, ln1_b + i * EMB, theta + i * NQB, qm, nullptr);
        // fused quantum FFN + residual
        ffnb_kernel<<<dim3(EMB / 128, MROWS / 128), 256, 0, stream>>>(
            qm, l1_w + (size_t)i * FDIM * NQB, l1_b + i * FDIM,
            wb_l2 + (size_t)i * EMB * FDIM, l2_b + i * EMB, h);
        // LN2 (+ bf16 copy for next block's QKV)
        ln_kernel<<<MROWS / 4, 256, 0, stream>>>(
            h, ln2_g + i * EMB, ln2_b + i * EMB, nullptr, nullptr, hb);
    }

    pool_cls_kernel<<<BATCH, EMB, 0, stream>>>(h, cls_w, cls_b, (float*)d_out);
}

// Round 3
// 2900.435 us; speedup vs baseline: 1.4867x; 1.0020x over previous
//
#include <hip/hip_runtime.h>
#include <math.h>

#define BATCH 256
#define SEQ   196
#define EMB   256
#define HEADS 8
#define HDIM  32
#define NBLK  4
#define FDIM  1024
#define NQB   8
#define NCLS  10
#define MROWS (BATCH*SEQ)   // 50176 = 392*128

typedef __attribute__((ext_vector_type(8))) short  short8;   // 8 bf16 (4 VGPRs)
typedef __attribute__((ext_vector_type(4))) float  floatx4;  // MFMA acc

// fp32 -> bf16 RNE
__device__ __forceinline__ unsigned short f2b(float f) {
    unsigned u = __builtin_bit_cast(unsigned, f);
    u += 0x7fffu + ((u >> 16) & 1u);
    return (unsigned short)(u >> 16);
}
// bf16 -> fp32
__device__ __forceinline__ float b2f(unsigned short u) {
    return __builtin_bit_cast(float, ((unsigned)u) << 16);
}

// async global->LDS, 16B per lane. LDS dest is wave-uniform base; HW adds lane*16.
__device__ __forceinline__ void gl_lds16(const void* g, void* l) {
    __builtin_amdgcn_global_load_lds(
        (const __attribute__((address_space(1))) unsigned int*)g,
        (__attribute__((address_space(3))) unsigned int*)l, 16, 0, 0);
}

// ------------------------------------------------------------------
// Positional encoding table
// ------------------------------------------------------------------
__global__ void pe_kernel(float* __restrict__ pe) {
    int s = blockIdx.x, e = threadIdx.x;
    int j2 = (e >> 1) * 2;
    float dv  = expf(-(float)j2 * (logf(10000.0f) / (float)EMB));
    float ang = (float)s * dv;
    pe[s * EMB + e] = (e & 1) ? cosf(ang) : sinf(ang);
}

// ------------------------------------------------------------------
// fp32 -> bf16 bulk convert (weights), n % 4 == 0
// ------------------------------------------------------------------
__global__ __launch_bounds__(256) void cvt_kernel(
    const float* __restrict__ src, unsigned short* __restrict__ dst, int n)
{
    int i = (blockIdx.x * 256 + threadIdx.x) * 4;
    if (i < n) {
        float4 v = *(const float4*)(src + i);
        ushort4 o;
        o.x = f2b(v.x); o.y = f2b(v.y); o.z = f2b(v.z); o.w = f2b(v.w);
        *(ushort4*)(dst + i) = o;
    }
}

// ------------------------------------------------------------------
// Fused conv+conv+reshape+embed+PE -> h (fp32) and hb (bf16)
// ------------------------------------------------------------------
__global__ __launch_bounds__(256) void embed_kernel(
    const float* __restrict__ x,   const float* __restrict__ qw,
    const float* __restrict__ qb,  const float* __restrict__ pw,
    const float* __restrict__ pb,  const float* __restrict__ ew,
    const float* __restrict__ eb,  const float* __restrict__ pe,
    float* __restrict__ h, unsigned short* __restrict__ hb)
{
    int bs = blockIdx.x;
    int b  = bs / SEQ;
    int s  = bs % SEQ;
    int e  = threadIdx.x;

    int co    = s / 49;
    int pbase = (s % 49) * 4;

    float feat[4];
#pragma unroll
    for (int c = 0; c < 4; ++c) {
        int p  = pbase + c;
        int hh = p / 14, ww = p % 14;
        float dw[4];
#pragma unroll
        for (int ci = 0; ci < 4; ++ci) {
            const float* xp = x + (((size_t)b * 4 + ci) * 28 + hh * 2) * 28 + ww * 2;
            dw[ci] = qb[ci] + xp[0]  * qw[ci * 4 + 0] + xp[1]  * qw[ci * 4 + 1]
                            + xp[28] * qw[ci * 4 + 2] + xp[29] * qw[ci * 4 + 3];
        }
        feat[c] = pb[co] + pw[co * 4 + 0] * dw[0] + pw[co * 4 + 1] * dw[1]
                         + pw[co * 4 + 2] * dw[2] + pw[co * 4 + 3] * dw[3];
    }

    float4 w4 = *(const float4*)(ew + e * 4);
    float v = eb[e] + feat[0] * w4.x + feat[1] * w4.y + feat[2] * w4.z + feat[3] * w4.w
            + pe[s * EMB + e];
    h[(size_t)bs * EMB + e]  = v;
    hb[(size_t)bs * EMB + e] = f2b(v);
}

// ------------------------------------------------------------------
// bf16 MFMA GEMM: C[M,N] = A[M,K]bf16 @ W[N,K]bf16^T + bias (+R).
// Output fp32 to C, or bf16 to Cb if Cb != nullptr.
// 128x128 tile, BK=32, 256 thr = 4 waves, each wave 64x64 via 4x4 16x16x32.
// ------------------------------------------------------------------
__global__ __launch_bounds__(256) void bgemm_kernel(
    const unsigned short* __restrict__ A, const unsigned short* __restrict__ W,
    const float* __restrict__ bias, const float* __restrict__ R,
    float* __restrict__ C, unsigned short* __restrict__ Cb, int M, int N, int K)
{
    __shared__ unsigned short As[128 * 32];
    __shared__ unsigned short Bs[128 * 32];

    int t = threadIdx.x;
    int w = t >> 6, l = t & 63;
    int quad = l >> 4, lane16 = l & 15;
    int m0 = blockIdx.y * 128, n0 = blockIdx.x * 128;
    int mq = (w & 1) * 64, nq = (w >> 1) * 64;

    int srow = w * 32 + (l >> 2);
    int scol = (l & 3) * 8;
    const unsigned short* Abase = A + (size_t)(m0 + srow) * K + scol;
    const unsigned short* Wbase = W + (size_t)(n0 + srow) * K + scol;
    unsigned short* AsW = As + w * 1024;
    unsigned short* BsW = Bs + w * 1024;

    floatx4 acc[4][4];
#pragma unroll
    for (int i = 0; i < 4; ++i)
#pragma unroll
        for (int j = 0; j < 4; ++j) acc[i][j] = (floatx4){0.f, 0.f, 0.f, 0.f};

    for (int k0 = 0; k0 < K; k0 += 32) {
        __syncthreads();
        gl_lds16(Abase + k0,                  AsW);
        gl_lds16(Abase + (size_t)16 * K + k0, AsW + 512);
        gl_lds16(Wbase + k0,                  BsW);
        gl_lds16(Wbase + (size_t)16 * K + k0, BsW + 512);
        __syncthreads();

        short8 af[4], bf[4];
#pragma unroll
        for (int i = 0; i < 4; ++i)
            af[i] = *(const short8*)&As[(mq + i * 16 + lane16) * 32 + quad * 8];
#pragma unroll
        for (int j = 0; j < 4; ++j)
            bf[j] = *(const short8*)&Bs[(nq + j * 16 + lane16) * 32 + quad * 8];
#pragma unroll
        for (int i = 0; i < 4; ++i)
#pragma unroll
            for (int j = 0; j < 4; ++j)
                acc[i][j] = __builtin_amdgcn_mfma_f32_16x16x32_bf16(
                                af[i], bf[j], acc[i][j], 0, 0, 0);
    }

#pragma unroll
    for (int j = 0; j < 4; ++j) {
        int col = n0 + nq + j * 16 + lane16;
        float bb = bias[col];
#pragma unroll
        for (int i = 0; i < 4; ++i) {
#pragma unroll
            for (int r = 0; r < 4; ++r) {
                int row = m0 + mq + i * 16 + quad * 4 + r;
                size_t off = (size_t)row * N + col;
                float v = acc[i][j][r] + bb;
                if (R) v += R[off];
                if (Cb) Cb[off] = f2b(v);
                else    C[off]  = v;
            }
        }
    }
}

// ------------------------------------------------------------------
// FFN activation: act[m,f] = relu(b1[f] + dot8(qm[m,:], l1w[f,:])), bf16 out.
// 2 rows per block; thread covers 8 consecutive f -> 16B coalesced store.
// ------------------------------------------------------------------
__global__ __launch_bounds__(256) void act_kernel(
    const float* __restrict__ qm, const float* __restrict__ l1w,
    const float* __restrict__ l1b, unsigned short* __restrict__ act)
{
    int t = threadIdx.x;
    int m = blockIdx.x * 2 + (t >> 7);
    int f = (t & 127) * 8;

    floatx4 q0 = *(const floatx4*)(qm + (size_t)m * NQB);
    floatx4 q1 = *(const floatx4*)(qm + (size_t)m * NQB + 4);

    unsigned short o[8];
#pragma unroll
    for (int u = 0; u < 8; ++u) {
        const floatx4* lp = (const floatx4*)(l1w + (size_t)(f + u) * NQB);
        floatx4 w0 = lp[0], w1 = lp[1];
        float a = l1b[f + u]
            + q0.x * w0.x + q0.y * w0.y + q0.z * w0.z + q0.w * w0.w
            + q1.x * w1.x + q1.y * w1.y + q1.z * w1.z + q1.w * w1.w;
        o[u] = f2b(fmaxf(a, 0.f));
    }
    *(short8*)(act + (size_t)m * FDIM + f) = *(short8*)o;
}

// ------------------------------------------------------------------
// Fused attention per (b,h): bf16 qkv in; K/V converted to fp32 LDS;
// one thread per query row, online softmax; bf16 out in (b,s,e).
// ------------------------------------------------------------------
__global__ __launch_bounds__(256) void attn_kernel(
    const unsigned short* __restrict__ qkv, unsigned short* __restrict__ ob)
{
    __shared__ float Ks[SEQ * HDIM];
    __shared__ float Vs[SEQ * HDIM];

    int bh = blockIdx.x;
    int b  = bh >> 3;
    int hh = bh & 7;
    const unsigned short* base = qkv + (size_t)b * SEQ * 768 + hh * HDIM;

    for (int idx = threadIdx.x; idx < (SEQ * HDIM) / 4; idx += 256) {
        int j = idx >> 3, d = (idx & 7) * 4;
        ushort4 kv = *(const ushort4*)(base + (size_t)j * 768 + 256 + d);
        ushort4 vv = *(const ushort4*)(base + (size_t)j * 768 + 512 + d);
        float4 kf = {b2f(kv.x), b2f(kv.y), b2f(kv.z), b2f(kv.w)};
        float4 vf = {b2f(vv.x), b2f(vv.y), b2f(vv.z), b2f(vv.w)};
        *(float4*)&Ks[j * HDIM + d] = kf;
        *(float4*)&Vs[j * HDIM + d] = vf;
    }
    __syncthreads();

    int s = threadIdx.x;
    if (s < SEQ) {
        float q[HDIM];
        const unsigned short* qp = base + (size_t)s * 768;
#pragma unroll
        for (int d = 0; d < HDIM; ++d) q[d] = b2f(qp[d]) * 0.17677669529663687f;

        float m = -1e30f, ll = 0.f;
        float acc[HDIM] = {};
        for (int j = 0; j < SEQ; ++j) {
            const float* kr = &Ks[j * HDIM];
            float sc = 0.f;
#pragma unroll
            for (int d = 0; d < HDIM; ++d) sc += q[d] * kr[d];
            float mn   = fmaxf(m, sc);
            float corr = __expf(m - mn);
            float p    = __expf(sc - mn);
            ll = ll * corr + p;
            const float* vr = &Vs[j * HDIM];
#pragma unroll
            for (int d = 0; d < HDIM; ++d) acc[d] = acc[d] * corr + p * vr[d];
            m = mn;
        }
        float invl = 1.f / ll;
        unsigned short* op = ob + ((size_t)b * SEQ + s) * EMB + hh * HDIM;
#pragma unroll
        for (int d = 0; d < HDIM; ++d) op[d] = f2b(acc[d] * invl);
    }
}

// ------------------------------------------------------------------
// LayerNorm, one wave per row, in place. Optionally emits qm (ln1)
// or a bf16 copy of the output row (ln2).
// ------------------------------------------------------------------
__global__ __launch_bounds__(256) void ln_kernel(
    float* __restrict__ h, const float* __restrict__ g,
    const float* __restrict__ bta, const float* __restrict__ theta,
    float* __restrict__ qm, unsigned short* __restrict__ hb)
{
    int wid  = threadIdx.x >> 6;
    int lane = threadIdx.x & 63;
    int row  = blockIdx.x * 4 + wid;

    float* hp = h + (size_t)row * EMB + lane * 4;
    float4 xv = *(const float4*)hp;

    float s1 = xv.x + xv.y + xv.z + xv.w;
    float s2 = xv.x * xv.x + xv.y * xv.y + xv.z * xv.z + xv.w * xv.w;
#pragma unroll
    for (int off = 32; off; off >>= 1) {
        s1 += __shfl_xor(s1, off);
        s2 += __shfl_xor(s2, off);
    }
    float mean = s1 * (1.0f / 256.0f);
    float var  = s2 * (1.0f / 256.0f) - mean * mean;
    float inv  = rsqrtf(var + 1e-5f);

    float4 gv = *(const float4*)(g   + lane * 4);
    float4 bv = *(const float4*)(bta + lane * 4);
    float4 y;
    y.x = (xv.x - mean) * inv * gv.x + bv.x;
    y.y = (xv.y - mean) * inv * gv.y + bv.y;
    y.z = (xv.z - mean) * inv * gv.z + bv.z;
    y.w = (xv.w - mean) * inv * gv.w + bv.w;
    *(float4*)hp = y;

    if (qm && lane < 2) {
        float yv[4] = {y.x, y.y, y.z, y.w};
        float* qp = qm + (size_t)row * NQB + lane * 4;
#pragma unroll
        for (int j = 0; j < 4; ++j)
            qp[j] = __cosf(yv[j]) * __cosf(theta[lane * 4 + j]);
    }
    if (hb) {
        ushort4 o4;
        o4.x = f2b(y.x); o4.y = f2b(y.y); o4.z = f2b(y.z); o4.w = f2b(y.w);
        *(ushort4*)(hb + (size_t)row * EMB + lane * 4) = o4;
    }
}

// ------------------------------------------------------------------
// Mean-pool over S then classifier.
// ------------------------------------------------------------------
__global__ __launch_bounds__(256) void pool_cls_kernel(
    const float* __restrict__ h, const float* __restrict__ cw,
    const float* __restrict__ cb, float* __restrict__ out)
{
    __shared__ float pooled[EMB];
    int b = blockIdx.x;
    int e = threadIdx.x;
    float s = 0.f;
    const float* hp = h + (size_t)b * SEQ * EMB + e;
    for (int j = 0; j < SEQ; ++j) s += hp[(size_t)j * EMB];
    pooled[e] = s * (1.0f / (float)SEQ);
    __syncthreads();
    if (e < NCLS) {
        float acc = cb[e];
        const float* wr = cw + e * EMB;
        for (int k = 0; k < EMB; ++k) acc += pooled[k] * wr[k];
        out[b * NCLS + e] = acc;
    }
}

// ------------------------------------------------------------------
extern "C" void kernel_launch(void* const* d_in, const int* in_sizes, int n_in,
                              void* d_out, int out_size, void* d_ws, size_t ws_size,
                              hipStream_t stream)
{
    const float* x         = (const float*)d_in[0];
    const float* qfilter_w = (const float*)d_in[1];
    const float* qfilter_b = (const float*)d_in[2];
    const float* pw_w      = (const float*)d_in[3];
    const float* pw_b      = (const float*)d_in[4];
    const float* embed_w   = (const float*)d_in[5];
    const float* embed_b   = (const float*)d_in[6];
    const float* in_proj_w = (const float*)d_in[7];
    const float* in_proj_b = (const float*)d_in[8];
    const float* out_w     = (const float*)d_in[9];
    const float* out_b     = (const float*)d_in[10];
    const float* theta     = (const float*)d_in[11];
    const float* l1_w      = (const float*)d_in[12];
    const float* l1_b      = (const float*)d_in[13];
    const float* l2_w      = (const float*)d_in[14];
    const float* l2_b      = (const float*)d_in[15];
    const float* ln1_g     = (const float*)d_in[16];
    const float* ln1_b     = (const float*)d_in[17];
    const float* ln2_g     = (const float*)d_in[18];
    const float* ln2_b     = (const float*)d_in[19];
    const float* cls_w     = (const float*)d_in[20];
    const float* cls_b     = (const float*)d_in[21];

    char* ws = (char*)d_ws;
    float* h   = (float*)ws;                   ws += (size_t)MROWS * EMB * 4;   // 51.4MB
    // big region time-shared: qkv bf16 [M,768] (77MB) then act bf16 [M,1024] (103MB)
    unsigned short* big = (unsigned short*)ws; ws += (size_t)MROWS * FDIM * 2;  // 102.8MB
    float* qm  = (float*)ws;                   ws += (size_t)MROWS * NQB * 4;   // 1.6MB
    float* pe  = (float*)ws;                   ws += (size_t)SEQ * EMB * 4;
    unsigned short* hb  = (unsigned short*)ws; ws += (size_t)MROWS * EMB * 2;   // 25.7MB
    unsigned short* ob  = (unsigned short*)ws; ws += (size_t)MROWS * EMB * 2;   // 25.7MB
    unsigned short* wb_in = (unsigned short*)ws; ws += (size_t)NBLK * 768 * EMB * 2;
    unsigned short* wb_o  = (unsigned short*)ws; ws += (size_t)NBLK * EMB * EMB * 2;
    unsigned short* wb_l2 = (unsigned short*)ws; ws += (size_t)NBLK * EMB * FDIM * 2;

    unsigned short* qkvb = big;
    unsigned short* act  = big;

    pe_kernel<<<SEQ, EMB, 0, stream>>>(pe);
    {
        int n1 = NBLK * 768 * EMB;
        int n2 = NBLK * EMB * EMB;
        int n3 = NBLK * EMB * FDIM;
        cvt_kernel<<<n1 / 1024, 256, 0, stream>>>(in_proj_w, wb_in, n1);
        cvt_kernel<<<n2 / 1024, 256, 0, stream>>>(out_w,     wb_o,  n2);
        cvt_kernel<<<n3 / 1024, 256, 0, stream>>>(l2_w,      wb_l2, n3);
    }

    embed_kernel<<<MROWS, 256, 0, stream>>>(x, qfilter_w, qfilter_b,
                                            pw_w, pw_b, embed_w, embed_b, pe, h, hb);

    for (int i = 0; i < NBLK; ++i) {
        // QKV projection -> bf16 [M,768]
        bgemm_kernel<<<dim3(6, MROWS / 128), 256, 0, stream>>>(
            hb, wb_in + (size_t)i * 768 * EMB, in_proj_b + i * 768,
            nullptr, nullptr, qkvb, MROWS, 768, EMB);
        // attention (bf16 in/out)
        attn_kernel<<<BATCH * HEADS, 256, 0, stream>>>(qkvb, ob);
        // out projection + residual: h = h + o @ W^T + b  (fp32 out)
        bgemm_kernel<<<dim3(2, MROWS / 128), 256, 0, stream>>>(
            ob, wb_o + (size_t)i * EMB * EMB, out_b + i * EMB,
            h, h, nullptr, MROWS, EMB, EMB);
        // LN1 (+ qm)
        ln_kernel<<<MROWS / 4, 256, 0, stream>>>(
            h, ln1_g + i * EMB, ln1_b + i * EMB, theta + i * NQB, qm, nullptr);
        // FFN: act = relu(qm @ l1^T + b1) (bf16), then h += act @ l2^T + b2
        act_kernel<<<MROWS / 2, 256, 0, stream>>>(
            qm, l1_w + (size_t)i * FDIM * NQB, l1_b + i * FDIM, act);
        bgemm_kernel<<<dim3(2, MROWS / 128), 256, 0, stream>>>(
            act, wb_l2 + (size_t)i * EMB * FDIM, l2_b + i * EMB,
            h, h, nullptr, MROWS, EMB, FDIM);
        // LN2 (+ bf16 copy for next block's QKV)
        ln_kernel<<<MROWS / 4, 256, 0, stream>>>(
            h, ln2_g + i * EMB, ln2_b + i * EMB, nullptr, nullptr, hb);
    }

    pool_cls_kernel<<<BATCH, EMB, 0, stream>>>(h, cls_w, cls_b, (float*)d_out);
}

// Round 4
// 2204.404 us; speedup vs baseline: 1.9561x; 1.3157x over previous
//
#include <hip/hip_runtime.h>
#include <math.h>

#define BATCH 256
#define SEQ   196
#define EMB   256
#define HEADS 8
#define HDIM  32
#define NBLK  4
#define FDIM  1024
#define NQB   8
#define NCLS  10
#define MROWS (BATCH*SEQ)   // 50176 = 392*128

typedef __attribute__((ext_vector_type(8))) short  short8;   // 8 bf16 (4 VGPRs)
typedef __attribute__((ext_vector_type(4))) float  floatx4;  // MFMA acc

// fp32 -> bf16 RNE
__device__ __forceinline__ unsigned short f2b(float f) {
    unsigned u = __builtin_bit_cast(unsigned, f);
    u += 0x7fffu + ((u >> 16) & 1u);
    return (unsigned short)(u >> 16);
}
// bf16 -> fp32
__device__ __forceinline__ float b2f(unsigned short u) {
    return __builtin_bit_cast(float, ((unsigned)u) << 16);
}

// async global->LDS, 16B per lane. LDS dest is wave-uniform base; HW adds lane*16.
__device__ __forceinline__ void gl_lds16(const void* g, void* l) {
    __builtin_amdgcn_global_load_lds(
        (const __attribute__((address_space(1))) unsigned int*)g,
        (__attribute__((address_space(3))) unsigned int*)l, 16, 0, 0);
}

// ------------------------------------------------------------------
// Positional encoding table
// ------------------------------------------------------------------
__global__ void pe_kernel(float* __restrict__ pe) {
    int s = blockIdx.x, e = threadIdx.x;
    int j2 = (e >> 1) * 2;
    float dv  = expf(-(float)j2 * (logf(10000.0f) / (float)EMB));
    float ang = (float)s * dv;
    pe[s * EMB + e] = (e & 1) ? cosf(ang) : sinf(ang);
}

// ------------------------------------------------------------------
// fp32 -> bf16 bulk convert (weights), n % 4 == 0
// ------------------------------------------------------------------
__global__ __launch_bounds__(256) void cvt_kernel(
    const float* __restrict__ src, unsigned short* __restrict__ dst, int n)
{
    int i = (blockIdx.x * 256 + threadIdx.x) * 4;
    if (i < n) {
        float4 v = *(const float4*)(src + i);
        ushort4 o;
        o.x = f2b(v.x); o.y = f2b(v.y); o.z = f2b(v.z); o.w = f2b(v.w);
        *(ushort4*)(dst + i) = o;
    }
}

// ------------------------------------------------------------------
// Fused conv+conv+reshape+embed+PE -> h (fp32) and hb (bf16)
// ------------------------------------------------------------------
__global__ __launch_bounds__(256) void embed_kernel(
    const float* __restrict__ x,   const float* __restrict__ qw,
    const float* __restrict__ qb,  const float* __restrict__ pw,
    const float* __restrict__ pb,  const float* __restrict__ ew,
    const float* __restrict__ eb,  const float* __restrict__ pe,
    float* __restrict__ h, unsigned short* __restrict__ hb)
{
    int bs = blockIdx.x;
    int b  = bs / SEQ;
    int s  = bs % SEQ;
    int e  = threadIdx.x;

    int co    = s / 49;
    int pbase = (s % 49) * 4;

    float feat[4];
#pragma unroll
    for (int c = 0; c < 4; ++c) {
        int p  = pbase + c;
        int hh = p / 14, ww = p % 14;
        float dw[4];
#pragma unroll
        for (int ci = 0; ci < 4; ++ci) {
            const float* xp = x + (((size_t)b * 4 + ci) * 28 + hh * 2) * 28 + ww * 2;
            dw[ci] = qb[ci] + xp[0]  * qw[ci * 4 + 0] + xp[1]  * qw[ci * 4 + 1]
                            + xp[28] * qw[ci * 4 + 2] + xp[29] * qw[ci * 4 + 3];
        }
        feat[c] = pb[co] + pw[co * 4 + 0] * dw[0] + pw[co * 4 + 1] * dw[1]
                         + pw[co * 4 + 2] * dw[2] + pw[co * 4 + 3] * dw[3];
    }

    float4 w4 = *(const float4*)(ew + e * 4);
    float v = eb[e] + feat[0] * w4.x + feat[1] * w4.y + feat[2] * w4.z + feat[3] * w4.w
            + pe[s * EMB + e];
    h[(size_t)bs * EMB + e]  = v;
    hb[(size_t)bs * EMB + e] = f2b(v);
}

// ------------------------------------------------------------------
// bf16 MFMA GEMM: C[M,N] = A[M,K]bf16 @ W[N,K]bf16^T + bias (+R).
// Output fp32 to C, or bf16 to Cb if Cb != nullptr.
// 128x128 tile, BK=32, 256 thr = 4 waves, each wave 64x64 via 4x4 16x16x32.
// ------------------------------------------------------------------
__global__ __launch_bounds__(256) void bgemm_kernel(
    const unsigned short* __restrict__ A, const unsigned short* __restrict__ W,
    const float* __restrict__ bias, const float* __restrict__ R,
    float* __restrict__ C, unsigned short* __restrict__ Cb, int M, int N, int K)
{
    __shared__ unsigned short As[128 * 32];
    __shared__ unsigned short Bs[128 * 32];

    int t = threadIdx.x;
    int w = t >> 6, l = t & 63;
    int quad = l >> 4, lane16 = l & 15;
    int m0 = blockIdx.y * 128, n0 = blockIdx.x * 128;
    int mq = (w & 1) * 64, nq = (w >> 1) * 64;

    int srow = w * 32 + (l >> 2);
    int scol = (l & 3) * 8;
    const unsigned short* Abase = A + (size_t)(m0 + srow) * K + scol;
    const unsigned short* Wbase = W + (size_t)(n0 + srow) * K + scol;
    unsigned short* AsW = As + w * 1024;
    unsigned short* BsW = Bs + w * 1024;

    floatx4 acc[4][4];
#pragma unroll
    for (int i = 0; i < 4; ++i)
#pragma unroll
        for (int j = 0; j < 4; ++j) acc[i][j] = (floatx4){0.f, 0.f, 0.f, 0.f};

    for (int k0 = 0; k0 < K; k0 += 32) {
        __syncthreads();
        gl_lds16(Abase + k0,                  AsW);
        gl_lds16(Abase + (size_t)16 * K + k0, AsW + 512);
        gl_lds16(Wbase + k0,                  BsW);
        gl_lds16(Wbase + (size_t)16 * K + k0, BsW + 512);
        __syncthreads();

        short8 af[4], bf[4];
#pragma unroll
        for (int i = 0; i < 4; ++i)
            af[i] = *(const short8*)&As[(mq + i * 16 + lane16) * 32 + quad * 8];
#pragma unroll
        for (int j = 0; j < 4; ++j)
            bf[j] = *(const short8*)&Bs[(nq + j * 16 + lane16) * 32 + quad * 8];
#pragma unroll
        for (int i = 0; i < 4; ++i)
#pragma unroll
            for (int j = 0; j < 4; ++j)
                acc[i][j] = __builtin_amdgcn_mfma_f32_16x16x32_bf16(
                                af[i], bf[j], acc[i][j], 0, 0, 0);
    }

#pragma unroll
    for (int j = 0; j < 4; ++j) {
        int col = n0 + nq + j * 16 + lane16;
        float bb = bias[col];
#pragma unroll
        for (int i = 0; i < 4; ++i) {
#pragma unroll
            for (int r = 0; r < 4; ++r) {
                int row = m0 + mq + i * 16 + quad * 4 + r;
                size_t off = (size_t)row * N + col;
                float v = acc[i][j][r] + bb;
                if (R) v += R[off];
                if (Cb) Cb[off] = f2b(v);
                else    C[off]  = v;
            }
        }
    }
}

// ------------------------------------------------------------------
// FFN activation: act[m,f] = relu(b1[f] + dot8(qm[m,:], l1w[f,:])), bf16 out.
// ------------------------------------------------------------------
__global__ __launch_bounds__(256) void act_kernel(
    const float* __restrict__ qm, const float* __restrict__ l1w,
    const float* __restrict__ l1b, unsigned short* __restrict__ act)
{
    int t = threadIdx.x;
    int m = blockIdx.x * 2 + (t >> 7);
    int f = (t & 127) * 8;

    floatx4 q0 = *(const floatx4*)(qm + (size_t)m * NQB);
    floatx4 q1 = *(const floatx4*)(qm + (size_t)m * NQB + 4);

    unsigned short o[8];
#pragma unroll
    for (int u = 0; u < 8; ++u) {
        const floatx4* lp = (const floatx4*)(l1w + (size_t)(f + u) * NQB);
        floatx4 w0 = lp[0], w1 = lp[1];
        float a = l1b[f + u]
            + q0.x * w0.x + q0.y * w0.y + q0.z * w0.z + q0.w * w0.w
            + q1.x * w1.x + q1.y * w1.y + q1.z * w1.z + q1.w * w1.w;
        o[u] = f2b(fmaxf(a, 0.f));
    }
    *(short8*)(act + (size_t)m * FDIM + f) = *(short8*)o;
}

// ------------------------------------------------------------------
// MFMA flash attention, one workgroup (4 waves) per (b,h).
// Q,K staged row-major bf16 [208][32]; V transposed [32][232];
// QK^T: one 16x16x32 MFMA per score tile (D=32=K). Full softmax per
// 16-row query tile (13 fragments in regs, 16-lane shuffle reduce).
// P -> per-wave LDS (A-operand layout), PV with V^T as B operand.
// Pads: keys>=196 masked to -1e30; Vt/Ps pad cols zeroed (no 0*NaN).
// ------------------------------------------------------------------
__global__ __launch_bounds__(256) void attn_kernel(
    const unsigned short* __restrict__ qkv, unsigned short* __restrict__ ob)
{
    __shared__ unsigned short Qs[208 * 32];    // 13 KB
    __shared__ unsigned short Ks[208 * 32];    // 13 KB
    __shared__ unsigned short Vt[32 * 232];    // 14.5 KB (stride 232: 16B-aligned rows)
    __shared__ unsigned short Ps[64 * 232];    // 29 KB, 16 rows per wave

    int t  = threadIdx.x;
    int bh = blockIdx.x;
    int b  = bh >> 3;
    int hh = bh & 7;
    const unsigned short* base = qkv + (size_t)b * SEQ * 768 + hh * HDIM;

    // stage Q,K row-major; V transposed
    for (int idx = t; idx < SEQ * 8; idx += 256) {
        int s = idx >> 3, d4 = (idx & 7) * 4;
        ushort4 qv = *(const ushort4*)(base + (size_t)s * 768 + d4);
        ushort4 kv = *(const ushort4*)(base + (size_t)s * 768 + 256 + d4);
        ushort4 vv = *(const ushort4*)(base + (size_t)s * 768 + 512 + d4);
        *(ushort4*)&Qs[s * 32 + d4] = qv;
        *(ushort4*)&Ks[s * 32 + d4] = kv;
        Vt[(d4 + 0) * 232 + s] = vv.x;
        Vt[(d4 + 1) * 232 + s] = vv.y;
        Vt[(d4 + 2) * 232 + s] = vv.z;
        Vt[(d4 + 3) * 232 + s] = vv.w;
    }
    // zero pads
    for (int idx = t; idx < 12 * 8; idx += 256) {          // Q/K rows 196..207
        int s = 196 + (idx >> 3), d4 = (idx & 7) * 4;
        ushort4 z = {0, 0, 0, 0};
        *(ushort4*)&Qs[s * 32 + d4] = z;
        *(ushort4*)&Ks[s * 32 + d4] = z;
    }
    for (int idx = t; idx < 32 * 36; idx += 256) {         // Vt cols 196..231
        int d = idx / 36, c = 196 + idx % 36;
        Vt[d * 232 + c] = 0;
    }
    for (int idx = t; idx < 64 * 24; idx += 256) {         // Ps cols 208..231
        int r = idx / 24, c = 208 + idx % 24;
        Ps[r * 232 + c] = 0;
    }
    __syncthreads();

    int w = t >> 6, l = t & 63;
    int quad = l >> 4, lane16 = l & 15;
    unsigned short* Pw = Ps + w * 16 * 232;

    for (int qt = w; qt < 13; qt += 4) {
        short8 af = *(const short8*)&Qs[(qt * 16 + lane16) * 32 + quad * 8];

        floatx4 sc[13];
#pragma unroll
        for (int kt = 0; kt < 13; ++kt) {
            short8 bf = *(const short8*)&Ks[(kt * 16 + lane16) * 32 + quad * 8];
            floatx4 z = {0.f, 0.f, 0.f, 0.f};
            sc[kt] = __builtin_amdgcn_mfma_f32_16x16x32_bf16(af, bf, z, 0, 0, 0);
        }

        // scale + key mask + row max (row = quad*4+r, cols spread over lane16)
        float mrow[4] = {-1e30f, -1e30f, -1e30f, -1e30f};
#pragma unroll
        for (int kt = 0; kt < 13; ++kt) {
#pragma unroll
            for (int r = 0; r < 4; ++r) {
                float v = sc[kt][r] * 0.17677669529663687f;
                if (kt == 12 && lane16 >= 4) v = -1e30f;   // keys 196..207
                sc[kt][r] = v;
                mrow[r] = fmaxf(mrow[r], v);
            }
        }
#pragma unroll
        for (int off = 8; off >= 1; off >>= 1)
#pragma unroll
            for (int r = 0; r < 4; ++r)
                mrow[r] = fmaxf(mrow[r], __shfl_xor(mrow[r], off));

        float lsum[4] = {0.f, 0.f, 0.f, 0.f};
#pragma unroll
        for (int kt = 0; kt < 13; ++kt) {
#pragma unroll
            for (int r = 0; r < 4; ++r) {
                float p = __expf(sc[kt][r] - mrow[r]);
                lsum[r] += p;
                Pw[(quad * 4 + r) * 232 + kt * 16 + lane16] = f2b(p);
            }
        }
#pragma unroll
        for (int off = 8; off >= 1; off >>= 1)
#pragma unroll
            for (int r = 0; r < 4; ++r)
                lsum[r] += __shfl_xor(lsum[r], off);

        // PV: O[16 x 32] = P[16 x 224] * V[224 x 32]
        floatx4 oacc[2] = {{0.f,0.f,0.f,0.f},{0.f,0.f,0.f,0.f}};
#pragma unroll
        for (int c = 0; c < 7; ++c) {
            short8 pa = *(const short8*)&Pw[lane16 * 232 + c * 32 + quad * 8];
#pragma unroll
            for (int nt = 0; nt < 2; ++nt) {
                short8 vb = *(const short8*)&Vt[(nt * 16 + lane16) * 232 + c * 32 + quad * 8];
                oacc[nt] = __builtin_amdgcn_mfma_f32_16x16x32_bf16(pa, vb, oacc[nt], 0, 0, 0);
            }
        }

#pragma unroll
        for (int r = 0; r < 4; ++r) {
            int srow = qt * 16 + quad * 4 + r;
            if (srow < SEQ) {
                float invl = 1.f / lsum[r];
                unsigned short* op = ob + ((size_t)b * SEQ + srow) * EMB + hh * HDIM;
                op[lane16]      = f2b(oacc[0][r] * invl);
                op[16 + lane16] = f2b(oacc[1][r] * invl);
            }
        }
    }
}

// ------------------------------------------------------------------
// LayerNorm, one wave per row, in place. Optionally emits qm (ln1)
// or a bf16 copy of the output row (ln2).
// ------------------------------------------------------------------
__global__ __launch_bounds__(256) void ln_kernel(
    float* __restrict__ h, const float* __restrict__ g,
    const float* __restrict__ bta, const float* __restrict__ theta,
    float* __restrict__ qm, unsigned short* __restrict__ hb)
{
    int wid  = threadIdx.x >> 6;
    int lane = threadIdx.x & 63;
    int row  = blockIdx.x * 4 + wid;

    float* hp = h + (size_t)row * EMB + lane * 4;
    float4 xv = *(const float4*)hp;

    float s1 = xv.x + xv.y + xv.z + xv.w;
    float s2 = xv.x * xv.x + xv.y * xv.y + xv.z * xv.z + xv.w * xv.w;
#pragma unroll
    for (int off = 32; off; off >>= 1) {
        s1 += __shfl_xor(s1, off);
        s2 += __shfl_xor(s2, off);
    }
    float mean = s1 * (1.0f / 256.0f);
    float var  = s2 * (1.0f / 256.0f) - mean * mean;
    float inv  = rsqrtf(var + 1e-5f);

    float4 gv = *(const float4*)(g   + lane * 4);
    float4 bv = *(const float4*)(bta + lane * 4);
    float4 y;
    y.x = (xv.x - mean) * inv * gv.x + bv.x;
    y.y = (xv.y - mean) * inv * gv.y + bv.y;
    y.z = (xv.z - mean) * inv * gv.z + bv.z;
    y.w = (xv.w - mean) * inv * gv.w + bv.w;
    *(float4*)hp = y;

    if (qm && lane < 2) {
        float yv[4] = {y.x, y.y, y.z, y.w};
        float* qp = qm + (size_t)row * NQB + lane * 4;
#pragma unroll
        for (int j = 0; j < 4; ++j)
            qp[j] = __cosf(yv[j]) * __cosf(theta[lane * 4 + j]);
    }
    if (hb) {
        ushort4 o4;
        o4.x = f2b(y.x); o4.y = f2b(y.y); o4.z = f2b(y.z); o4.w = f2b(y.w);
        *(ushort4*)(hb + (size_t)row * EMB + lane * 4) = o4;
    }
}

// ------------------------------------------------------------------
// Mean-pool over S then classifier.
// ------------------------------------------------------------------
__global__ __launch_bounds__(256) void pool_cls_kernel(
    const float* __restrict__ h, const float* __restrict__ cw,
    const float* __restrict__ cb, float* __restrict__ out)
{
    __shared__ float pooled[EMB];
    int b = blockIdx.x;
    int e = threadIdx.x;
    float s = 0.f;
    const float* hp = h + (size_t)b * SEQ * EMB + e;
    for (int j = 0; j < SEQ; ++j) s += hp[(size_t)j * EMB];
    pooled[e] = s * (1.0f / (float)SEQ);
    __syncthreads();
    if (e < NCLS) {
        float acc = cb[e];
        const float* wr = cw + e * EMB;
        for (int k = 0; k < EMB; ++k) acc += pooled[k] * wr[k];
        out[b * NCLS + e] = acc;
    }
}

// ------------------------------------------------------------------
extern "C" void kernel_launch(void* const* d_in, const int* in_sizes, int n_in,
                              void* d_out, int out_size, void* d_ws, size_t ws_size,
                              hipStream_t stream)
{
    const float* x         = (const float*)d_in[0];
    const float* qfilter_w = (const float*)d_in[1];
    const float* qfilter_b = (const float*)d_in[2];
    const float* pw_w      = (const float*)d_in[3];
    const float* pw_b      = (const float*)d_in[4];
    const float* embed_w   = (const float*)d_in[5];
    const float* embed_b   = (const float*)d_in[6];
    const float* in_proj_w = (const float*)d_in[7];
    const float* in_proj_b = (const float*)d_in[8];
    const float* out_w     = (const float*)d_in[9];
    const float* out_b     = (const float*)d_in[10];
    const float* theta     = (const float*)d_in[11];
    const float* l1_w      = (const float*)d_in[12];
    const float* l1_b      = (const float*)d_in[13];
    const float* l2_w      = (const float*)d_in[14];
    const float* l2_b      = (const float*)d_in[15];
    const float* ln1_g     = (const float*)d_in[16];
    const float* ln1_b     = (const float*)d_in[17];
    const float* ln2_g     = (const float*)d_in[18];
    const float* ln2_b     = (const float*)d_in[19];
    const float* cls_w     = (const float*)d_in[20];
    const float* cls_b     = (const float*)d_in[21];

    char* ws = (char*)d_ws;
    float* h   = (float*)ws;                   ws += (size_t)MROWS * EMB * 4;   // 51.4MB
    // big region time-shared: qkv bf16 [M,768] (77MB) then act bf16 [M,1024] (103MB)
    unsigned short* big = (unsigned short*)ws; ws += (size_t)MROWS * FDIM * 2;  // 102.8MB
    float* qm  = (float*)ws;                   ws += (size_t)MROWS * NQB * 4;   // 1.6MB
    float* pe  = (float*)ws;                   ws += (size_t)SEQ * EMB * 4;
    unsigned short* hb  = (unsigned short*)ws; ws += (size_t)MROWS * EMB * 2;   // 25.7MB
    unsigned short* ob  = (unsigned short*)ws; ws += (size_t)MROWS * EMB * 2;   // 25.7MB
    unsigned short* wb_in = (unsigned short*)ws; ws += (size_t)NBLK * 768 * EMB * 2;
    unsigned short* wb_o  = (unsigned short*)ws; ws += (size_t)NBLK * EMB * EMB * 2;
    unsigned short* wb_l2 = (unsigned short*)ws; ws += (size_t)NBLK * EMB * FDIM * 2;

    unsigned short* qkvb = big;
    unsigned short* act  = big;

    pe_kernel<<<SEQ, EMB, 0, stream>>>(pe);
    {
        int n1 = NBLK * 768 * EMB;
        int n2 = NBLK * EMB * EMB;
        int n3 = NBLK * EMB * FDIM;
        cvt_kernel<<<n1 / 1024, 256, 0, stream>>>(in_proj_w, wb_in, n1);
        cvt_kernel<<<n2 / 1024, 256, 0, stream>>>(out_w,     wb_o,  n2);
        cvt_kernel<<<n3 / 1024, 256, 0, stream>>>(l2_w,      wb_l2, n3);
    }

    embed_kernel<<<MROWS, 256, 0, stream>>>(x, qfilter_w, qfilter_b,
                                            pw_w, pw_b, embed_w, embed_b, pe, h, hb);

    for (int i = 0; i < NBLK; ++i) {
        // QKV projection -> bf16 [M,768]
        bgemm_kernel<<<dim3(6, MROWS / 128), 256, 0, stream>>>(
            hb, wb_in + (size_t)i * 768 * EMB, in_proj_b + i * 768,
            nullptr, nullptr, qkvb, MROWS, 768, EMB);
        // MFMA flash attention (bf16 in/out)
        attn_kernel<<<BATCH * HEADS, 256, 0, stream>>>(qkvb, ob);
        // out projection + residual: h = h + o @ W^T + b  (fp32 out)
        bgemm_kernel<<<dim3(2, MROWS / 128), 256, 0, stream>>>(
            ob, wb_o + (size_t)i * EMB * EMB, out_b + i * EMB,
            h, h, nullptr, MROWS, EMB, EMB);
        // LN1 (+ qm)
        ln_kernel<<<MROWS / 4, 256, 0, stream>>>(
            h, ln1_g + i * EMB, ln1_b + i * EMB, theta + i * NQB, qm, nullptr);
        // FFN: act = relu(qm @ l1^T + b1) (bf16), then h += act @ l2^T + b2
        act_kernel<<<MROWS / 2, 256, 0, stream>>>(
            qm, l1_w + (size_t)i * FDIM * NQB, l1_b + i * FDIM, act);
        bgemm_kernel<<<dim3(2, MROWS / 128), 256, 0, stream>>>(
            act, wb_l2 + (size_t)i * EMB * FDIM, l2_b + i * EMB,
            h, h, nullptr, MROWS, EMB, FDIM);
        // LN2 (+ bf16 copy for next block's QKV)
        ln_kernel<<<MROWS / 4, 256, 0, stream>>>(
            h, ln2_g + i * EMB, ln2_b + i * EMB, nullptr, nullptr, hb);
    }

    pool_cls_kernel<<<BATCH, EMB, 0, stream>>>(h, cls_w, cls_b, (float*)d_out);
}

// Round 5
// 1425.716 us; speedup vs baseline: 3.0245x; 1.5462x over previous
//
#include <hip/hip_runtime.h>
#include <math.h>

#define BATCH 256
#define SEQ   196
#define EMB   256
#define HEADS 8
#define HDIM  32
#define NBLK  4
#define FDIM  1024
#define NQB   8
#define NCLS  10
#define MROWS (BATCH*SEQ)   // 50176 = 392*128 = 784*64

typedef __attribute__((ext_vector_type(8))) short  short8;   // 8 bf16 (4 VGPRs)
typedef __attribute__((ext_vector_type(4))) float  floatx4;  // MFMA acc

// fp32 -> bf16 RNE
__device__ __forceinline__ unsigned short f2b(float f) {
    unsigned u = __builtin_bit_cast(unsigned, f);
    u += 0x7fffu + ((u >> 16) & 1u);
    return (unsigned short)(u >> 16);
}
// bf16 -> fp32
__device__ __forceinline__ float b2f(unsigned short u) {
    return __builtin_bit_cast(float, ((unsigned)u) << 16);
}

// async global->LDS, 16B per lane. LDS dest is wave-uniform base; HW adds lane*16.
__device__ __forceinline__ void gl_lds16(const void* g, void* l) {
    __builtin_amdgcn_global_load_lds(
        (const __attribute__((address_space(1))) unsigned int*)g,
        (__attribute__((address_space(3))) unsigned int*)l, 16, 0, 0);
}

// ------------------------------------------------------------------
// Positional encoding table
// ------------------------------------------------------------------
__global__ void pe_kernel(float* __restrict__ pe) {
    int s = blockIdx.x, e = threadIdx.x;
    int j2 = (e >> 1) * 2;
    float dv  = expf(-(float)j2 * (logf(10000.0f) / (float)EMB));
    float ang = (float)s * dv;
    pe[s * EMB + e] = (e & 1) ? cosf(ang) : sinf(ang);
}

// ------------------------------------------------------------------
// fp32 -> bf16 bulk convert (weights), n % 4 == 0
// ------------------------------------------------------------------
__global__ __launch_bounds__(256) void cvt_kernel(
    const float* __restrict__ src, unsigned short* __restrict__ dst, int n)
{
    int i = (blockIdx.x * 256 + threadIdx.x) * 4;
    if (i < n) {
        float4 v = *(const float4*)(src + i);
        ushort4 o;
        o.x = f2b(v.x); o.y = f2b(v.y); o.z = f2b(v.z); o.w = f2b(v.w);
        *(ushort4*)(dst + i) = o;
    }
}

// ------------------------------------------------------------------
// l1_w [NBLK][FDIM][NQB] -> l1wT [NBLK][NQB][FDIM]  (fp32, 32K elems)
// ------------------------------------------------------------------
__global__ __launch_bounds__(256) void l1t_kernel(
    const float* __restrict__ src, float* __restrict__ dst)
{
    int idx = blockIdx.x * 256 + threadIdx.x;   // (i*FDIM + f)*NQB + q
    int i = idx >> 13, rem = idx & 8191;
    int q = rem & 7, f = rem >> 3;
    dst[((size_t)i * NQB + q) * FDIM + f] = src[idx];
}

// ------------------------------------------------------------------
// Fused conv+conv+reshape+embed+PE -> h (fp32) and hb (bf16)
// ------------------------------------------------------------------
__global__ __launch_bounds__(256) void embed_kernel(
    const float* __restrict__ x,   const float* __restrict__ qw,
    const float* __restrict__ qb,  const float* __restrict__ pw,
    const float* __restrict__ pb,  const float* __restrict__ ew,
    const float* __restrict__ eb,  const float* __restrict__ pe,
    float* __restrict__ h, unsigned short* __restrict__ hb)
{
    int bs = blockIdx.x;
    int b  = bs / SEQ;
    int s  = bs % SEQ;
    int e  = threadIdx.x;

    int co    = s / 49;
    int pbase = (s % 49) * 4;

    float feat[4];
#pragma unroll
    for (int c = 0; c < 4; ++c) {
        int p  = pbase + c;
        int hh = p / 14, ww = p % 14;
        float dw[4];
#pragma unroll
        for (int ci = 0; ci < 4; ++ci) {
            const float* xp = x + (((size_t)b * 4 + ci) * 28 + hh * 2) * 28 + ww * 2;
            dw[ci] = qb[ci] + xp[0]  * qw[ci * 4 + 0] + xp[1]  * qw[ci * 4 + 1]
                            + xp[28] * qw[ci * 4 + 2] + xp[29] * qw[ci * 4 + 3];
        }
        feat[c] = pb[co] + pw[co * 4 + 0] * dw[0] + pw[co * 4 + 1] * dw[1]
                         + pw[co * 4 + 2] * dw[2] + pw[co * 4 + 3] * dw[3];
    }

    float4 w4 = *(const float4*)(ew + e * 4);
    float v = eb[e] + feat[0] * w4.x + feat[1] * w4.y + feat[2] * w4.z + feat[3] * w4.w
            + pe[s * EMB + e];
    h[(size_t)bs * EMB + e]  = v;
    hb[(size_t)bs * EMB + e] = f2b(v);
}

// ------------------------------------------------------------------
// bf16 MFMA GEMM (qkv): C = A @ W^T + bias, bf16 out.
// 128x128 tile, BK=32, 4 waves x 4x4 16x16x32 frags.
// ------------------------------------------------------------------
__global__ __launch_bounds__(256) void bgemm_kernel(
    const unsigned short* __restrict__ A, const unsigned short* __restrict__ W,
    const float* __restrict__ bias, unsigned short* __restrict__ Cb,
    int M, int N, int K)
{
    __shared__ unsigned short As[128 * 32];
    __shared__ unsigned short Bs[128 * 32];

    int t = threadIdx.x;
    int w = t >> 6, l = t & 63;
    int quad = l >> 4, lane16 = l & 15;
    int m0 = blockIdx.y * 128, n0 = blockIdx.x * 128;
    int mq = (w & 1) * 64, nq = (w >> 1) * 64;

    int srow = w * 32 + (l >> 2);
    int scol = (l & 3) * 8;
    const unsigned short* Abase = A + (size_t)(m0 + srow) * K + scol;
    const unsigned short* Wbase = W + (size_t)(n0 + srow) * K + scol;
    unsigned short* AsW = As + w * 1024;
    unsigned short* BsW = Bs + w * 1024;

    floatx4 acc[4][4];
#pragma unroll
    for (int i = 0; i < 4; ++i)
#pragma unroll
        for (int j = 0; j < 4; ++j) acc[i][j] = (floatx4){0.f, 0.f, 0.f, 0.f};

    for (int k0 = 0; k0 < K; k0 += 32) {
        __syncthreads();
        gl_lds16(Abase + k0,                  AsW);
        gl_lds16(Abase + (size_t)16 * K + k0, AsW + 512);
        gl_lds16(Wbase + k0,                  BsW);
        gl_lds16(Wbase + (size_t)16 * K + k0, BsW + 512);
        __syncthreads();

        short8 af[4], bf[4];
#pragma unroll
        for (int i = 0; i < 4; ++i)
            af[i] = *(const short8*)&As[(mq + i * 16 + lane16) * 32 + quad * 8];
#pragma unroll
        for (int j = 0; j < 4; ++j)
            bf[j] = *(const short8*)&Bs[(nq + j * 16 + lane16) * 32 + quad * 8];
#pragma unroll
        for (int i = 0; i < 4; ++i)
#pragma unroll
            for (int j = 0; j < 4; ++j)
                acc[i][j] = __builtin_amdgcn_mfma_f32_16x16x32_bf16(
                                af[i], bf[j], acc[i][j], 0, 0, 0);
    }

#pragma unroll
    for (int j = 0; j < 4; ++j) {
        int col = n0 + nq + j * 16 + lane16;
        float bb = bias[col];
#pragma unroll
        for (int i = 0; i < 4; ++i) {
#pragma unroll
            for (int r = 0; r < 4; ++r) {
                int row = m0 + mq + i * 16 + quad * 4 + r;
                Cb[(size_t)row * N + col] = f2b(acc[i][j][r] + bb);
            }
        }
    }
}

// ------------------------------------------------------------------
// Fused GEMM + bias + residual + LayerNorm (+qm / +hb emit).
// C_pre = A[M,K] @ W[256,K]^T + bias + h ;  h = LN(C_pre)*g + beta
// BM=64, BN=256 (full rows in-block -> in-block LN reduction).
// 4 waves; wave w owns cols [w*64, w*64+64), all 64 rows.
// ------------------------------------------------------------------
__global__ __launch_bounds__(256) void bgemm_ln_kernel(
    const unsigned short* __restrict__ A, const unsigned short* __restrict__ W,
    const float* __restrict__ bias, const float* __restrict__ g,
    const float* __restrict__ beta, const float* __restrict__ theta,
    float* __restrict__ h, unsigned short* __restrict__ hb,
    float* __restrict__ qm, int K)
{
    __shared__ unsigned short As[64 * 32];     // 4 KB
    __shared__ unsigned short Bs[256 * 32];    // 16 KB
    __shared__ float redS[64][4], redQ[64][4]; // per-wave row partials
    __shared__ float mrow[64], irow[64];

    int t = threadIdx.x;
    int w = t >> 6, l = t & 63;
    int quad = l >> 4, lane16 = l & 15;
    int m0 = blockIdx.x * 64;

    // staging: wave w -> A rows [w*16, w*16+16), B rows [w*64, w*64+64)
    const unsigned short* Abase = A + (size_t)(m0 + w * 16 + (l >> 2)) * K + (l & 3) * 8;
    const unsigned short* Wbase = W + (size_t)(w * 64 + (l >> 2)) * K + (l & 3) * 8;
    unsigned short* AsW = As + w * 512;
    unsigned short* BsW = Bs + w * 64 * 32;

    floatx4 acc[4][4];
#pragma unroll
    for (int i = 0; i < 4; ++i)
#pragma unroll
        for (int j = 0; j < 4; ++j) acc[i][j] = (floatx4){0.f, 0.f, 0.f, 0.f};

    for (int k0 = 0; k0 < K; k0 += 32) {
        __syncthreads();
        gl_lds16(Abase + k0, AsW);
#pragma unroll
        for (int c = 0; c < 4; ++c)
            gl_lds16(Wbase + (size_t)c * 16 * K + k0, BsW + c * 512);
        __syncthreads();

        short8 af[4], bf[4];
#pragma unroll
        for (int i = 0; i < 4; ++i)
            af[i] = *(const short8*)&As[(i * 16 + lane16) * 32 + quad * 8];
#pragma unroll
        for (int j = 0; j < 4; ++j)
            bf[j] = *(const short8*)&Bs[(w * 64 + j * 16 + lane16) * 32 + quad * 8];
#pragma unroll
        for (int i = 0; i < 4; ++i)
#pragma unroll
            for (int j = 0; j < 4; ++j)
                acc[i][j] = __builtin_amdgcn_mfma_f32_16x16x32_bf16(
                                af[i], bf[j], acc[i][j], 0, 0, 0);
    }

    // ---- epilogue: v = acc + bias + residual; LN stats in-block ----
    float bb[4];
#pragma unroll
    for (int j = 0; j < 4; ++j) bb[j] = bias[w * 64 + j * 16 + lane16];

#pragma unroll
    for (int i = 0; i < 4; ++i) {
#pragma unroll
        for (int r = 0; r < 4; ++r) {
            int row = i * 16 + quad * 4 + r;
            const float* hp = h + (size_t)(m0 + row) * EMB;
            float s1 = 0.f, s2 = 0.f;
#pragma unroll
            for (int j = 0; j < 4; ++j) {
                float v = acc[i][j][r] + bb[j] + hp[w * 64 + j * 16 + lane16];
                acc[i][j][r] = v;
                s1 += v;
                s2 += v * v;
            }
#pragma unroll
            for (int off = 8; off >= 1; off >>= 1) {
                s1 += __shfl_xor(s1, off);
                s2 += __shfl_xor(s2, off);
            }
            if (lane16 == 0) { redS[row][w] = s1; redQ[row][w] = s2; }
        }
    }
    __syncthreads();

    if (t < 64) {
        float s1 = redS[t][0] + redS[t][1] + redS[t][2] + redS[t][3];
        float s2 = redQ[t][0] + redQ[t][1] + redQ[t][2] + redQ[t][3];
        float mean = s1 * (1.0f / 256.0f);
        float var  = s2 * (1.0f / 256.0f) - mean * mean;
        mrow[t] = mean;
        irow[t] = rsqrtf(var + 1e-5f);
    }
    __syncthreads();

    float gv[4], bv[4];
#pragma unroll
    for (int j = 0; j < 4; ++j) {
        int col = w * 64 + j * 16 + lane16;
        gv[j] = g[col];
        bv[j] = beta[col];
    }

#pragma unroll
    for (int i = 0; i < 4; ++i) {
#pragma unroll
        for (int r = 0; r < 4; ++r) {
            int row  = i * 16 + quad * 4 + r;
            float mean = mrow[row], inv = irow[row];
            size_t base = (size_t)(m0 + row) * EMB;
#pragma unroll
            for (int j = 0; j < 4; ++j) {
                int col = w * 64 + j * 16 + lane16;
                float y = (acc[i][j][r] - mean) * inv * gv[j] + bv[j];
                h[base + col] = y;
                if (hb) hb[base + col] = f2b(y);
                if (qm && w == 0 && j == 0 && lane16 < NQB)
                    qm[(size_t)(m0 + row) * NQB + lane16] =
                        __cosf(y) * __cosf(theta[lane16]);
            }
        }
    }
}

// ------------------------------------------------------------------
// FFN activation: act[m,f] = relu(b1[f] + dot8(qm[m,:], l1wT[:,f]))
// l1wT fp32 [NQB][FDIM] -> lane-stride-16B fully coalesced loads.
// One block per row m; thread covers 4 consecutive f.
// ------------------------------------------------------------------
__global__ __launch_bounds__(256) void act_kernel(
    const float* __restrict__ qm, const float* __restrict__ l1wT,
    const float* __restrict__ l1b, unsigned short* __restrict__ act)
{
    int m = blockIdx.x;
    int f = threadIdx.x * 4;

    floatx4 q0 = *(const floatx4*)(qm + (size_t)m * NQB);
    floatx4 q1 = *(const floatx4*)(qm + (size_t)m * NQB + 4);
    float qv[8] = {q0.x, q0.y, q0.z, q0.w, q1.x, q1.y, q1.z, q1.w};

    float4 a = *(const float4*)(l1b + f);
#pragma unroll
    for (int j = 0; j < 8; ++j) {
        float4 wv = *(const float4*)(l1wT + (size_t)j * FDIM + f);
        a.x += qv[j] * wv.x; a.y += qv[j] * wv.y;
        a.z += qv[j] * wv.z; a.w += qv[j] * wv.w;
    }
    ushort4 o;
    o.x = f2b(fmaxf(a.x, 0.f)); o.y = f2b(fmaxf(a.y, 0.f));
    o.z = f2b(fmaxf(a.z, 0.f)); o.w = f2b(fmaxf(a.w, 0.f));
    *(ushort4*)(act + (size_t)m * FDIM + f) = o;
}

// ------------------------------------------------------------------
// MFMA flash attention, one workgroup (4 waves) per (b,h).
// ------------------------------------------------------------------
__global__ __launch_bounds__(256) void attn_kernel(
    const unsigned short* __restrict__ qkv, unsigned short* __restrict__ ob)
{
    __shared__ unsigned short Qs[208 * 32];
    __shared__ unsigned short Ks[208 * 32];
    __shared__ unsigned short Vt[32 * 232];
    __shared__ unsigned short Ps[64 * 232];

    int t  = threadIdx.x;
    int bh = blockIdx.x;
    int b  = bh >> 3;
    int hh = bh & 7;
    const unsigned short* base = qkv + (size_t)b * SEQ * 768 + hh * HDIM;

    for (int idx = t; idx < SEQ * 8; idx += 256) {
        int s = idx >> 3, d4 = (idx & 7) * 4;
        ushort4 qv = *(const ushort4*)(base + (size_t)s * 768 + d4);
        ushort4 kv = *(const ushort4*)(base + (size_t)s * 768 + 256 + d4);
        ushort4 vv = *(const ushort4*)(base + (size_t)s * 768 + 512 + d4);
        *(ushort4*)&Qs[s * 32 + d4] = qv;
        *(ushort4*)&Ks[s * 32 + d4] = kv;
        Vt[(d4 + 0) * 232 + s] = vv.x;
        Vt[(d4 + 1) * 232 + s] = vv.y;
        Vt[(d4 + 2) * 232 + s] = vv.z;
        Vt[(d4 + 3) * 232 + s] = vv.w;
    }
    for (int idx = t; idx < 12 * 8; idx += 256) {
        int s = 196 + (idx >> 3), d4 = (idx & 7) * 4;
        ushort4 z = {0, 0, 0, 0};
        *(ushort4*)&Qs[s * 32 + d4] = z;
        *(ushort4*)&Ks[s * 32 + d4] = z;
    }
    for (int idx = t; idx < 32 * 36; idx += 256) {
        int d = idx / 36, c = 196 + idx % 36;
        Vt[d * 232 + c] = 0;
    }
    for (int idx = t; idx < 64 * 24; idx += 256) {
        int r = idx / 24, c = 208 + idx % 24;
        Ps[r * 232 + c] = 0;
    }
    __syncthreads();

    int w = t >> 6, l = t & 63;
    int quad = l >> 4, lane16 = l & 15;
    unsigned short* Pw = Ps + w * 16 * 232;

    for (int qt = w; qt < 13; qt += 4) {
        short8 af = *(const short8*)&Qs[(qt * 16 + lane16) * 32 + quad * 8];

        floatx4 sc[13];
#pragma unroll
        for (int kt = 0; kt < 13; ++kt) {
            short8 bf = *(const short8*)&Ks[(kt * 16 + lane16) * 32 + quad * 8];
            floatx4 z = {0.f, 0.f, 0.f, 0.f};
            sc[kt] = __builtin_amdgcn_mfma_f32_16x16x32_bf16(af, bf, z, 0, 0, 0);
        }

        float mr[4] = {-1e30f, -1e30f, -1e30f, -1e30f};
#pragma unroll
        for (int kt = 0; kt < 13; ++kt) {
#pragma unroll
            for (int r = 0; r < 4; ++r) {
                float v = sc[kt][r] * 0.17677669529663687f;
                if (kt == 12 && lane16 >= 4) v = -1e30f;
                sc[kt][r] = v;
                mr[r] = fmaxf(mr[r], v);
            }
        }
#pragma unroll
        for (int off = 8; off >= 1; off >>= 1)
#pragma unroll
            for (int r = 0; r < 4; ++r)
                mr[r] = fmaxf(mr[r], __shfl_xor(mr[r], off));

        float lsum[4] = {0.f, 0.f, 0.f, 0.f};
#pragma unroll
        for (int kt = 0; kt < 13; ++kt) {
#pragma unroll
            for (int r = 0; r < 4; ++r) {
                float p = __expf(sc[kt][r] - mr[r]);
                lsum[r] += p;
                Pw[(quad * 4 + r) * 232 + kt * 16 + lane16] = f2b(p);
            }
        }
#pragma unroll
        for (int off = 8; off >= 1; off >>= 1)
#pragma unroll
            for (int r = 0; r < 4; ++r)
                lsum[r] += __shfl_xor(lsum[r], off);

        floatx4 oacc[2] = {{0.f,0.f,0.f,0.f},{0.f,0.f,0.f,0.f}};
#pragma unroll
        for (int c = 0; c < 7; ++c) {
            short8 pa = *(const short8*)&Pw[lane16 * 232 + c * 32 + quad * 8];
#pragma unroll
            for (int nt = 0; nt < 2; ++nt) {
                short8 vb = *(const short8*)&Vt[(nt * 16 + lane16) * 232 + c * 32 + quad * 8];
                oacc[nt] = __builtin_amdgcn_mfma_f32_16x16x32_bf16(pa, vb, oacc[nt], 0, 0, 0);
            }
        }

#pragma unroll
        for (int r = 0; r < 4; ++r) {
            int srow = qt * 16 + quad * 4 + r;
            if (srow < SEQ) {
                float invl = 1.f / lsum[r];
                unsigned short* op = ob + ((size_t)b * SEQ + srow) * EMB + hh * HDIM;
                op[lane16]      = f2b(oacc[0][r] * invl);
                op[16 + lane16] = f2b(oacc[1][r] * invl);
            }
        }
    }
}

// ------------------------------------------------------------------
// Mean-pool over S then classifier.
// ------------------------------------------------------------------
__global__ __launch_bounds__(256) void pool_cls_kernel(
    const float* __restrict__ h, const float* __restrict__ cw,
    const float* __restrict__ cb, float* __restrict__ out)
{
    __shared__ float pooled[EMB];
    int b = blockIdx.x;
    int e = threadIdx.x;
    float s = 0.f;
    const float* hp = h + (size_t)b * SEQ * EMB + e;
    for (int j = 0; j < SEQ; ++j) s += hp[(size_t)j * EMB];
    pooled[e] = s * (1.0f / (float)SEQ);
    __syncthreads();
    if (e < NCLS) {
        float acc = cb[e];
        const float* wr = cw + e * EMB;
        for (int k = 0; k < EMB; ++k) acc += pooled[k] * wr[k];
        out[b * NCLS + e] = acc;
    }
}

// ------------------------------------------------------------------
extern "C" void kernel_launch(void* const* d_in, const int* in_sizes, int n_in,
                              void* d_out, int out_size, void* d_ws, size_t ws_size,
                              hipStream_t stream)
{
    const float* x         = (const float*)d_in[0];
    const float* qfilter_w = (const float*)d_in[1];
    const float* qfilter_b = (const float*)d_in[2];
    const float* pw_w      = (const float*)d_in[3];
    const float* pw_b      = (const float*)d_in[4];
    const float* embed_w   = (const float*)d_in[5];
    const float* embed_b   = (const float*)d_in[6];
    const float* in_proj_w = (const float*)d_in[7];
    const float* in_proj_b = (const float*)d_in[8];
    const float* out_w     = (const float*)d_in[9];
    const float* out_b     = (const float*)d_in[10];
    const float* theta     = (const float*)d_in[11];
    const float* l1_w      = (const float*)d_in[12];
    const float* l1_b      = (const float*)d_in[13];
    const float* l2_w      = (const float*)d_in[14];
    const float* l2_b      = (const float*)d_in[15];
    const float* ln1_g     = (const float*)d_in[16];
    const float* ln1_b     = (const float*)d_in[17];
    const float* ln2_g     = (const float*)d_in[18];
    const float* ln2_b     = (const float*)d_in[19];
    const float* cls_w     = (const float*)d_in[20];
    const float* cls_b     = (const float*)d_in[21];

    char* ws = (char*)d_ws;
    float* h   = (float*)ws;                   ws += (size_t)MROWS * EMB * 4;   // 51.4MB
    // big region time-shared: qkv bf16 [M,768] (77MB) then act bf16 [M,1024] (103MB)
    unsigned short* big = (unsigned short*)ws; ws += (size_t)MROWS * FDIM * 2;  // 102.8MB
    float* qm  = (float*)ws;                   ws += (size_t)MROWS * NQB * 4;   // 1.6MB
    float* pe  = (float*)ws;                   ws += (size_t)SEQ * EMB * 4;
    unsigned short* hb  = (unsigned short*)ws; ws += (size_t)MROWS * EMB * 2;   // 25.7MB
    unsigned short* ob  = (unsigned short*)ws; ws += (size_t)MROWS * EMB * 2;   // 25.7MB
    unsigned short* wb_in = (unsigned short*)ws; ws += (size_t)NBLK * 768 * EMB * 2;
    unsigned short* wb_o  = (unsigned short*)ws; ws += (size_t)NBLK * EMB * EMB * 2;
    unsigned short* wb_l2 = (unsigned short*)ws; ws += (size_t)NBLK * EMB * FDIM * 2;
    float* l1wT = (float*)ws;                  ws += (size_t)NBLK * NQB * FDIM * 4;

    unsigned short* qkvb = big;
    unsigned short* act  = big;

    pe_kernel<<<SEQ, EMB, 0, stream>>>(pe);
    {
        int n1 = NBLK * 768 * EMB;
        int n2 = NBLK * EMB * EMB;
        int n3 = NBLK * EMB * FDIM;
        cvt_kernel<<<n1 / 1024, 256, 0, stream>>>(in_proj_w, wb_in, n1);
        cvt_kernel<<<n2 / 1024, 256, 0, stream>>>(out_w,     wb_o,  n2);
        cvt_kernel<<<n3 / 1024, 256, 0, stream>>>(l2_w,      wb_l2, n3);
        l1t_kernel<<<(NBLK * FDIM * NQB) / 256, 256, 0, stream>>>(l1_w, l1wT);
    }

    embed_kernel<<<MROWS, 256, 0, stream>>>(x, qfilter_w, qfilter_b,
                                            pw_w, pw_b, embed_w, embed_b, pe, h, hb);

    for (int i = 0; i < NBLK; ++i) {
        // QKV projection -> bf16 [M,768]
        bgemm_kernel<<<dim3(6, MROWS / 128), 256, 0, stream>>>(
            hb, wb_in + (size_t)i * 768 * EMB, in_proj_b + i * 768,
            qkvb, MROWS, 768, EMB);
        // MFMA flash attention (bf16 in/out)
        attn_kernel<<<BATCH * HEADS, 256, 0, stream>>>(qkvb, ob);
        // out-proj + residual + LN1 + qm  (h updated in place)
        bgemm_ln_kernel<<<MROWS / 64, 256, 0, stream>>>(
            ob, wb_o + (size_t)i * EMB * EMB, out_b + i * EMB,
            ln1_g + i * EMB, ln1_b + i * EMB, theta + i * NQB,
            h, nullptr, qm, EMB);
        // FFN activation (coalesced, l1wT)
        act_kernel<<<MROWS, 256, 0, stream>>>(
            qm, l1wT + (size_t)i * NQB * FDIM, l1_b + i * FDIM, act);
        // FFN l2 + residual + LN2 + hb for next layer's QKV
        bgemm_ln_kernel<<<MROWS / 64, 256, 0, stream>>>(
            act, wb_l2 + (size_t)i * EMB * FDIM, l2_b + i * EMB,
            ln2_g + i * EMB, ln2_b + i * EMB, nullptr,
            h, hb, nullptr, FDIM);
    }

    pool_cls_kernel<<<BATCH, EMB, 0, stream>>>(h, cls_w, cls_b, (float*)d_out);
}